// Round 8
// baseline (340.758 us; speedup 1.0000x reference)
//
#include <hip/hip_runtime.h>

#define S_LEN 2048
#define DMODEL 1024
#define NHEADS 16
#define DKH 64

typedef __attribute__((ext_vector_type(8))) short bf16x8;
typedef __attribute__((ext_vector_type(4))) short bf16x4;
typedef __attribute__((ext_vector_type(4))) float f32x4;

#if __has_builtin(__builtin_amdgcn_exp2f)
#define EXP2F(x) __builtin_amdgcn_exp2f(x)
#define QSCALE (0.125f * 1.44269504f)
#else
#define EXP2F(x) __expf(x)
#define QSCALE 0.125f
#endif

static __device__ __forceinline__ short f2bf(float f) {
    unsigned b = __float_as_uint(f);
    b = (b + 0x7FFFu + ((b >> 16) & 1u)) >> 16;   // RNE
    return (short)b;
}

// pack truncated-bf16 of (lo,hi) into one u32
static __device__ __forceinline__ unsigned pktrunc(float lo, float hi) {
#if __has_builtin(__builtin_amdgcn_perm)
    return __builtin_amdgcn_perm(__float_as_uint(hi), __float_as_uint(lo), 0x07060302u);
#else
    return (__float_as_uint(lo) >> 16) | (__float_as_uint(hi) & 0xFFFF0000u);
#endif
}

static __device__ __forceinline__ f32x4 mfma16(bf16x8 a, bf16x8 b, f32x4 c) {
    return __builtin_amdgcn_mfma_f32_16x16x32_bf16(a, b, c, 0, 0, 0);
}

static __device__ __forceinline__ bf16x8 cat44(bf16x4 a, bf16x4 b) {
    bf16x8 r;
    r[0] = a[0]; r[1] = a[1]; r[2] = a[2]; r[3] = a[3];
    r[4] = b[0]; r[5] = b[1]; r[6] = b[2]; r[7] = b[3];
    return r;
}

static __device__ __forceinline__ void glds16(const short* g, short* l) {
    __builtin_amdgcn_global_load_lds(
        (const __attribute__((address_space(1))) void*)g,
        (__attribute__((address_space(3))) void*)l, 16, 0, 0);
}

// ---------------------------------------------------------------------------
// prep: fused fp32->bf16 convert (blocks 0..8191) + mask bit-pack (2048 blocks)
// ---------------------------------------------------------------------------
struct CvtArgs { const float* src[7]; short* dst[7]; };

__global__ __launch_bounds__(256) void prep(CvtArgs a, const int* __restrict__ mask,
                                            unsigned long long* __restrict__ mw) {
    if (blockIdx.x < 8192) {
        const size_t i8 = ((size_t)blockIdx.x * 256 + threadIdx.x) * 8;
        int seg; size_t off;
        if (i8 < ((size_t)12 << 20)) { seg = (int)(i8 >> 22); off = i8 & ((1u << 22) - 1); }
        else { size_t r = i8 - ((size_t)12 << 20); seg = 3 + (int)(r >> 20); off = r & ((1u << 20) - 1); }
        const float* s = a.src[seg] + off;
        float4 x0 = *(const float4*)s, x1 = *(const float4*)(s + 4);
        short o[8];
        o[0] = f2bf(x0.x); o[1] = f2bf(x0.y); o[2] = f2bf(x0.z); o[3] = f2bf(x0.w);
        o[4] = f2bf(x1.x); o[5] = f2bf(x1.y); o[6] = f2bf(x1.z); o[7] = f2bf(x1.w);
        *(uint4*)(a.dst[seg] + off) = *(uint4*)o;
    } else {
        const int wv = ((blockIdx.x - 8192) << 2) + (threadIdx.x >> 6);
        const int lane = threadIdx.x & 63;
        const size_t base = (size_t)wv << 4;
        #pragma unroll 4
        for (int it = 0; it < 16; ++it) {
            const size_t w = base + it;
            const int m = mask[(w << 6) + lane];
            unsigned long long bal = __ballot(m != 0);
            if (lane == 0) mw[w] = bal;
        }
    }
}

// ---------------------------------------------------------------------------
// C = X @ W^T + bias (bf16, m97-style), 128x128 tile, BK=32, glds16 staging.
// MODE 0: z<2 -> bf16 headed [BH][S][DKH] (scaled); z==2 -> TRANSPOSED headed
// kt[bh][d][s] (bias indexed by m-row = output feature, block m/n roles
// swapped so grid stays (32,8,3)). MODE 1: fp32 flat [M][N].
// ---------------------------------------------------------------------------
struct GemmArgs { const short* X[3]; const short* W[3]; const float* B[3];
                  void* C[3]; float scale[3]; };

template <int MODE>
__global__ __launch_bounds__(256) void gemm_bt(GemmArgs a) {
    __shared__ short Ah[128 * 32];
    __shared__ short Bh[128 * 32];
    const int z = blockIdx.z;
    const short* X = a.X[z];
    const short* W = a.W[z];
    const float* bias = a.B[z];
    const float scl = a.scale[z];

    const int t = threadIdx.x, wid = t >> 6, lane = t & 63;
    const int l15 = lane & 15, lq = lane >> 4;
    int m0, n0;
    if (MODE == 0 && z == 2) { m0 = blockIdx.y << 7; n0 = blockIdx.x << 7; }
    else                     { m0 = blockIdx.x << 7; n0 = blockIdx.y << 7; }
    const int wm = (wid >> 1) << 6, wn = (wid & 1) << 6;

    const int kb = (lane & 3) ^ ((lane >> 3) & 3);
    const int r0 = (wid << 5) + (lane >> 2);
    const short* ag0 = X + (size_t)(m0 + r0) * 1024 + (kb << 3);
    const short* ag1 = ag0 + 16 * 1024;
    const short* bg0 = W + (size_t)(n0 + r0) * 1024 + (kb << 3);
    const short* bg1 = bg0 + 16 * 1024;
    short* lA0 = Ah + (wid << 5) * 32;
    short* lA1 = lA0 + 16 * 32;
    short* lB0 = Bh + (wid << 5) * 32;
    short* lB1 = lB0 + 16 * 32;

    const int fpos = (lq ^ ((l15 >> 1) & 3)) << 3;

    f32x4 acc[4][4] = {};

    for (int k0 = 0; k0 < 1024; k0 += 32) {
        __syncthreads();
        glds16(ag0, lA0); glds16(ag1, lA1);
        glds16(bg0, lB0); glds16(bg1, lB1);
        ag0 += 32; ag1 += 32; bg0 += 32; bg1 += 32;
        __syncthreads();

        bf16x8 af[4], bfr[4];
        #pragma unroll
        for (int i = 0; i < 4; ++i)
            af[i] = *(const bf16x8*)&Ah[(wm + i * 16 + l15) * 32 + fpos];
        #pragma unroll
        for (int j = 0; j < 4; ++j)
            bfr[j] = *(const bf16x8*)&Bh[(wn + j * 16 + l15) * 32 + fpos];
        #pragma unroll
        for (int i = 0; i < 4; ++i)
            #pragma unroll
            for (int j = 0; j < 4; ++j)
                acc[i][j] = mfma16(af[i], bfr[j], acc[i][j]);
    }

    if (MODE == 0 && z == 2) {
        // transposed headed write: kt[(b*16+h)*64+d][s], o = m-row feature
        #pragma unroll
        for (int i = 0; i < 4; ++i) {
            #pragma unroll
            for (int r = 0; r < 4; ++r) {
                const int o = m0 + wm + i * 16 + (lq << 2) + r;
                const float bo_ = bias[o];
                const int h = o >> 6, d = o & 63;
                #pragma unroll
                for (int j = 0; j < 4; ++j) {
                    const int n = n0 + wn + j * 16 + l15;
                    const int bb = n >> 11, s = n & 2047;
                    ((short*)a.C[2])[(((size_t)((bb * 16 + h) << 6) + d) << 11) + s] =
                        f2bf(acc[i][j][r] + bo_);
                }
            }
        }
        return;
    }

    #pragma unroll
    for (int j = 0; j < 4; ++j) {
        const int n = n0 + wn + j * 16 + l15;
        const float bn = bias[n];
        #pragma unroll
        for (int i = 0; i < 4; ++i) {
            const int mbase = m0 + wm + i * 16 + (lq << 2);
            #pragma unroll
            for (int r = 0; r < 4; ++r) {
                const float val = (acc[i][j][r] + bn) * scl;
                const int m = mbase + r;
                if (MODE == 0) {
                    const int b = m >> 11, s = m & 2047, h = n >> 6, d = n & 63;
                    ((short*)a.C[z])[((((size_t)(b * 16 + h)) << 11) + s) * 64 + d] = f2bf(val);
                } else {
                    ((float*)a.C[z])[((size_t)m << 10) + n] = val;
                }
            }
        }
    }
}

// ---------------------------------------------------------------------------
// attn4: transposed-S flash attention (reference K/V swap). S^T = V@Q^T via
// 16x16x32 (C-layout col=i=l15, row=j=lq*4+r) -> exp'd scores ARE the
// A-fragments of PV MFMAs (zero P LDS traffic). l via MFMA against all-ones B.
// V and kt staged in LDS with 16B XOR swizzle. j-split z=2; partials merged
// by `combine`. Block: 4 waves x 32 i-rows = 128 rows; grid (16, 32, 2).
// K32 PV/lsum (v6): paf pairs concat into 16x16x32 A-frags.
//
// v7: 2-phase static-dual-buffer pipeline. v1/v6 issued the 4 glds16
// immediately before the barrier that drains them (syncthreads emits
// vmcnt(0)) -> full staging latency exposed every jc, 2 barriers/jc.
// Now: FOUR distinct static __shared__ arrays (Vs0/Vs1/Ks0/Ks1, alias
// analysis can prove glds writes to next buffer don't touch current
// buffer's ds_reads -> no early drain, unlike v2/v3's runtime buf[cur]),
// manually 2-phase-unrolled loop, STAGE(next) issued BEFORE compute(cur),
// ONE syncthreads per jc at the end: its mandatory vmcnt(0) lands after
// ~2000cy of compute, so the stage latency is hidden. No inline asm.
// ---------------------------------------------------------------------------
__global__ __launch_bounds__(256, 4) void attn4(
    const short* __restrict__ Qh, const short* __restrict__ Vh,
    const short* __restrict__ Kt, const unsigned long long* __restrict__ MW,
    short* __restrict__ Opart, float* __restrict__ lpart)
{
    __shared__ short Vs0[64 * 64];   // [j][d], 16B-chunk xor-swizzled
    __shared__ short Vs1[64 * 64];
    __shared__ short Ks0[64 * 64];   // [d][j], 16B-chunk xor-swizzled
    __shared__ short Ks1[64 * 64];

    const int t = threadIdx.x, wid = t >> 6, lane = t & 63;
    const int l15 = lane & 15, lq = lane >> 4;
    const int bh = blockIdx.y, b = bh >> 4;
    const int z = blockIdx.z;
    const int ib = (blockIdx.x << 7) + (wid << 5);
    const int jbase = z << 10;

    // Q B-frags: B[n=i][k=d], rows ib + it*16 + l15
    bf16x8 qf[2][2];
    #pragma unroll
    for (int it = 0; it < 2; ++it) {
        const short* qp = Qh + ((size_t)bh * 2048 + ib + it * 16 + l15) * 64 + (lq << 3);
        qf[it][0] = *(const bf16x8*)qp;
        qf[it][1] = *(const bf16x8*)(qp + 32);
    }

    // staging: each wave stages 16 rows of V and 16 d-rows of Kt
    const int sr = lane >> 3, pc = lane & 7;
    const int lc = pc ^ sr;                      // logical 16B chunk
    const int wr = wid << 4;
    const short* vsrc = Vh + (size_t)bh * 131072 + (size_t)(jbase + wr + sr) * 64 + (lc << 3);
    const short* ksrc = Kt + (size_t)bh * 131072 + (size_t)(wr + sr) * 2048 + jbase + (lc << 3);
    const int ldso = wr << 6;                    // wave's LDS row base (shorts)

    const unsigned long long* mwp0 = MW + ((size_t)b * 2048 + ib + l15) * 32 + (z << 4);
    const unsigned long long* mwp1 = mwp0 + (size_t)16 * 32;

    const int x7 = l15 & 7;
    int voff[2], koff[4];
    #pragma unroll
    for (int p = 0; p < 2; ++p) voff[p] = (((p << 2) + lq) ^ x7) << 3;
    #pragma unroll
    for (int jt = 0; jt < 4; ++jt) {
        const int c8 = (jt << 2) + lq;           // logical 8B chunk
        koff[jt] = (((c8 >> 1) ^ x7) << 3) + ((c8 & 1) << 2);
    }

    f32x4 O[2][4] = {};
    f32x4 lsum[2] = {};
    bf16x8 ones8;
    #pragma unroll
    for (int e = 0; e < 8; ++e) ones8[e] = (short)0x3F80;

    uint2 mc0, mc1;

#define STAGE(VD, KD) do {                                       \
        glds16(vsrc, (VD) + ldso);                               \
        glds16(vsrc + 512, (VD) + ldso + 512);                   \
        glds16(ksrc, (KD) + ldso);                               \
        glds16(ksrc + 8 * 2048, (KD) + ldso + 512);              \
        vsrc += 4096; ksrc += 64;                                \
    } while (0)

#define ABODY(VB, KB, VN, KN, JC, STG) do {                                   \
        uint2 mn0, mn1;                                                       \
        if (STG) {                                                            \
            mn0 = *(const uint2*)(mwp0 + (JC) + 1);                           \
            mn1 = *(const uint2*)(mwp1 + (JC) + 1);                           \
            STAGE(VN, KN);                                                    \
        }                                                                     \
        __builtin_amdgcn_sched_barrier(0);                                    \
        /* V A-frags from VB */                                               \
        bf16x8 vf[4][2];                                                      \
        _Pragma("unroll")                                                     \
        for (int jt = 0; jt < 4; ++jt) {                                      \
            const short* vp = (VB) + (((jt << 4) + l15) << 6);                \
            vf[jt][0] = *(const bf16x8*)(vp + voff[0]);                       \
            vf[jt][1] = *(const bf16x8*)(vp + voff[1]);                       \
        }                                                                     \
        /* S^T -> exp -> packed K32 P A-frags, l via ones-MFMA */             \
        bf16x8 pa[2][2];                                                      \
        _Pragma("unroll")                                                     \
        for (int it = 0; it < 2; ++it) {                                      \
            const unsigned wx = (it ? mc1 : mc0).x, wy = (it ? mc1 : mc0).y;  \
            _Pragma("unroll")                                                 \
            for (int b2 = 0; b2 < 2; ++b2) {                                  \
                uint4 uu4;                                                    \
                unsigned* uw = (unsigned*)&uu4;                               \
                _Pragma("unroll")                                             \
                for (int h = 0; h < 2; ++h) {                                 \
                    const int jt = (b2 << 1) + h;                             \
                    f32x4 sc = {};                                            \
                    sc = mfma16(vf[jt][0], qf[it][0], sc);                    \
                    sc = mfma16(vf[jt][1], qf[it][1], sc);                    \
                    const unsigned w32 = (jt < 2) ? wx : wy;                  \
                    float p[4];                                               \
                    _Pragma("unroll")                                         \
                    for (int r = 0; r < 4; ++r) {                             \
                        const unsigned bit =                                  \
                            (w32 >> (((jt & 1) << 4) + (lq << 2) + r)) & 1u;  \
                        const float e = EXP2F(sc[r]);                         \
                        p[r] = bit ? e : 0.f;                                 \
                    }                                                         \
                    uw[(h << 1) + 0] = pktrunc(p[0], p[1]);                   \
                    uw[(h << 1) + 1] = pktrunc(p[2], p[3]);                   \
                }                                                             \
                pa[it][b2] = __builtin_bit_cast(bf16x8, uu4);                 \
                lsum[it] = mfma16(pa[it][b2], ones8, lsum[it]);               \
            }                                                                 \
        }                                                                     \
        /* O += P @ K from KB */                                              \
        _Pragma("unroll")                                                     \
        for (int dt = 0; dt < 4; ++dt) {                                      \
            const short* kp = (KB) + (((dt << 4) + l15) << 6);                \
            _Pragma("unroll")                                                 \
            for (int b2 = 0; b2 < 2; ++b2) {                                  \
                const bf16x4 k0 = *(const bf16x4*)(kp + koff[(b2 << 1) + 0]); \
                const bf16x4 k1 = *(const bf16x4*)(kp + koff[(b2 << 1) + 1]); \
                const bf16x8 kk = cat44(k0, k1);                              \
                O[0][dt] = mfma16(pa[0][b2], kk, O[0][dt]);                   \
                O[1][dt] = mfma16(pa[1][b2], kk, O[1][dt]);                   \
            }                                                                 \
        }                                                                     \
        __syncthreads();                                                      \
        if (STG) { mc0 = mn0; mc1 = mn1; }                                    \
    } while (0)

    // prologue: masks + tile 0 into buffer 0
    mc0 = *(const uint2*)mwp0;
    mc1 = *(const uint2*)mwp1;
    STAGE(Vs0, Ks0);
    __syncthreads();

    for (int jc = 0; jc < 14; jc += 2) {
        ABODY(Vs0, Ks0, Vs1, Ks1, jc, 1);
        ABODY(Vs1, Ks1, Vs0, Ks0, jc + 1, 1);
    }
    ABODY(Vs0, Ks0, Vs1, Ks1, 14, 1);
    ABODY(Vs1, Ks1, Vs0, Ks0, 15, 0);

#undef ABODY
#undef STAGE

    // epilogue: rows i = lq*4+r; cols d = dt*16+l15; l duplicated across l15
    const size_t zb = (size_t)((z << 5) + bh) * 2048;
    #pragma unroll
    for (int it = 0; it < 2; ++it) {
        const int rb = ib + (it << 4) + (lq << 2);
        if (l15 == 0) {
            #pragma unroll
            for (int r = 0; r < 4; ++r)
                lpart[zb + rb + r] = lsum[it][r];
        }
        #pragma unroll
        for (int dt = 0; dt < 4; ++dt)
            #pragma unroll
            for (int r = 0; r < 4; ++r)
                Opart[(zb + rb + r) * 64 + (dt << 4) + l15] = f2bf(O[it][dt][r]);
    }
}

// ---------------------------------------------------------------------------
// combine: attr[b][s][h*64+d] = (O0+O1)/(l0+l1), bf16 out
// ---------------------------------------------------------------------------
__global__ __launch_bounds__(256) void combine(const short* __restrict__ Op,
                                               const float* __restrict__ lp,
                                               short* __restrict__ attr) {
    const int idx = blockIdx.x * 256 + threadIdx.x;      // 524288 total
    const int d8 = (idx & 7) << 3;
    const int srow = (idx >> 3) & 2047;
    const int bh = idx >> 14, b = bh >> 4, h = bh & 15;
    const size_t r0 = (size_t)bh * 2048 + srow;
    const size_t r1 = r0 + (size_t)32 * 2048;
    uint4 a = *(const uint4*)(Op + r0 * 64 + d8);
    uint4 c = *(const uint4*)(Op + r1 * 64 + d8);
    const float inv = 1.f / (lp[r0] + lp[r1]);
    const unsigned* au = (const unsigned*)&a;
    const unsigned* cu = (const unsigned*)&c;
    short o[8];
    #pragma unroll
    for (int i = 0; i < 4; ++i) {
        const float a0 = __uint_as_float(au[i] << 16);
        const float a1 = __uint_as_float(au[i] & 0xFFFF0000u);
        const float c0 = __uint_as_float(cu[i] << 16);
        const float c1 = __uint_as_float(cu[i] & 0xFFFF0000u);
        o[2 * i + 0] = f2bf((a0 + c0) * inv);
        o[2 * i + 1] = f2bf((a1 + c1) * inv);
    }
    *(uint4*)&attr[((size_t)b * 2048 + srow) * 1024 + (h << 6) + d8] = *(uint4*)o;
}

// ---------------------------------------------------------------------------
extern "C" void kernel_launch(void* const* d_in, const int* in_sizes, int n_in,
                              void* d_out, int out_size, void* d_ws, size_t ws_size,
                              hipStream_t stream) {
    const float* value = (const float*)d_in[0];
    const float* key   = (const float*)d_in[1];
    const float* query = (const float*)d_in[2];
    const int*   mask  = (const int*)d_in[3];
    const float* bv = (const float*)d_in[5];
    const float* bk = (const float*)d_in[7];
    const float* bq = (const float*)d_in[9];
    const float* bo = (const float*)d_in[11];
    float* out = (float*)d_out;

    const size_t M1 = (size_t)1 << 20, M4 = (size_t)1 << 22;
    short* ws = (short*)d_ws;
    short* Xq = ws;                       // reused as attr after proj
    short* Xk = ws + M4;                  // reused as Opart after proj (2*M4)
    short* Xv = ws + 2 * M4;
    short* Wc0 = ws + 3 * M4;             // reused as lpart after proj
    short* Wc1 = Wc0 + M1;
    short* Wc2 = Wc1 + M1;
    short* Wc3 = Wc2 + M1;
    short* qh = ws + 4 * M4;
    short* kt = ws + 5 * M4;
    short* vh = ws + 6 * M4;
    unsigned long long* maskw = (unsigned long long*)(ws + 7 * M4);
    short* attr = Xq;
    short* Opart = Xk;
    float* lpart = (float*)Wc0;

    CvtArgs cv;
    cv.src[0] = query; cv.dst[0] = Xq;
    cv.src[1] = key;   cv.dst[1] = Xk;
    cv.src[2] = value; cv.dst[2] = Xv;
    cv.src[3] = (const float*)d_in[8];  cv.dst[3] = Wc0;  // Wq
    cv.src[4] = (const float*)d_in[6];  cv.dst[4] = Wc1;  // Wk
    cv.src[5] = (const float*)d_in[4];  cv.dst[5] = Wc2;  // Wv
    cv.src[6] = (const float*)d_in[10]; cv.dst[6] = Wc3;  // Wo
    prep<<<10240, 256, 0, stream>>>(cv, mask, maskw);

    GemmArgs g1;
    g1.X[0] = Xq;  g1.W[0] = Wc0; g1.B[0] = bq; g1.C[0] = qh; g1.scale[0] = QSCALE;
    g1.X[1] = Xv;  g1.W[1] = Wc2; g1.B[1] = bv; g1.C[1] = vh; g1.scale[1] = 1.f;
    g1.X[2] = Wc1; g1.W[2] = Xk;  g1.B[2] = bk; g1.C[2] = kt; g1.scale[2] = 1.f;  // transposed K
    gemm_bt<0><<<dim3(32, 8, 3), 256, 0, stream>>>(g1);

    attn4<<<dim3(16, 32, 2), 256, 0, stream>>>(qh, vh, kt, maskw, Opart, lpart);

    combine<<<2048, 256, 0, stream>>>(Opart, lpart, attr);

    GemmArgs g2;
    g2.X[0] = attr; g2.W[0] = Wc3; g2.B[0] = bo; g2.C[0] = out; g2.scale[0] = 1.f;
    g2.X[1] = attr; g2.W[1] = Wc3; g2.B[1] = bo; g2.C[1] = out; g2.scale[1] = 1.f;
    g2.X[2] = attr; g2.W[2] = Wc3; g2.B[2] = bo; g2.C[2] = out; g2.scale[2] = 1.f;
    gemm_bt<1><<<dim3(32, 8, 1), 256, 0, stream>>>(g2);
}

// Round 9
// 281.445 us; speedup vs baseline: 1.2107x; 1.2107x over previous
//
#include <hip/hip_runtime.h>

#define S_LEN 2048
#define DMODEL 1024
#define NHEADS 16
#define DKH 64

typedef __attribute__((ext_vector_type(8))) short bf16x8;
typedef __attribute__((ext_vector_type(4))) short bf16x4;
typedef __attribute__((ext_vector_type(4))) float f32x4;

#if __has_builtin(__builtin_amdgcn_exp2f)
#define EXP2F(x) __builtin_amdgcn_exp2f(x)
#define QSCALE (0.125f * 1.44269504f)
#else
#define EXP2F(x) __expf(x)
#define QSCALE 0.125f
#endif

static __device__ __forceinline__ short f2bf(float f) {
    unsigned b = __float_as_uint(f);
    b = (b + 0x7FFFu + ((b >> 16) & 1u)) >> 16;   // RNE
    return (short)b;
}

// pack truncated-bf16 of (lo,hi) into one u32
static __device__ __forceinline__ unsigned pktrunc(float lo, float hi) {
#if __has_builtin(__builtin_amdgcn_perm)
    return __builtin_amdgcn_perm(__float_as_uint(hi), __float_as_uint(lo), 0x07060302u);
#else
    return (__float_as_uint(lo) >> 16) | (__float_as_uint(hi) & 0xFFFF0000u);
#endif
}

static __device__ __forceinline__ f32x4 mfma16(bf16x8 a, bf16x8 b, f32x4 c) {
    return __builtin_amdgcn_mfma_f32_16x16x32_bf16(a, b, c, 0, 0, 0);
}

static __device__ __forceinline__ bf16x8 cat44(bf16x4 a, bf16x4 b) {
    bf16x8 r;
    r[0] = a[0]; r[1] = a[1]; r[2] = a[2]; r[3] = a[3];
    r[4] = b[0]; r[5] = b[1]; r[6] = b[2]; r[7] = b[3];
    return r;
}

static __device__ __forceinline__ void glds16(const short* g, short* l) {
    __builtin_amdgcn_global_load_lds(
        (const __attribute__((address_space(1))) void*)g,
        (__attribute__((address_space(3))) void*)l, 16, 0, 0);
}

// ---------------------------------------------------------------------------
// prep: fused fp32->bf16 convert (blocks 0..8191) + mask bit-pack (2048 blocks)
// ---------------------------------------------------------------------------
struct CvtArgs { const float* src[7]; short* dst[7]; };

__global__ __launch_bounds__(256) void prep(CvtArgs a, const int* __restrict__ mask,
                                            unsigned long long* __restrict__ mw) {
    if (blockIdx.x < 8192) {
        const size_t i8 = ((size_t)blockIdx.x * 256 + threadIdx.x) * 8;
        int seg; size_t off;
        if (i8 < ((size_t)12 << 20)) { seg = (int)(i8 >> 22); off = i8 & ((1u << 22) - 1); }
        else { size_t r = i8 - ((size_t)12 << 20); seg = 3 + (int)(r >> 20); off = r & ((1u << 20) - 1); }
        const float* s = a.src[seg] + off;
        float4 x0 = *(const float4*)s, x1 = *(const float4*)(s + 4);
        short o[8];
        o[0] = f2bf(x0.x); o[1] = f2bf(x0.y); o[2] = f2bf(x0.z); o[3] = f2bf(x0.w);
        o[4] = f2bf(x1.x); o[5] = f2bf(x1.y); o[6] = f2bf(x1.z); o[7] = f2bf(x1.w);
        *(uint4*)(a.dst[seg] + off) = *(uint4*)o;
    } else {
        const int wv = ((blockIdx.x - 8192) << 2) + (threadIdx.x >> 6);
        const int lane = threadIdx.x & 63;
        const size_t base = (size_t)wv << 4;
        #pragma unroll 4
        for (int it = 0; it < 16; ++it) {
            const size_t w = base + it;
            const int m = mask[(w << 6) + lane];
            unsigned long long bal = __ballot(m != 0);
            if (lane == 0) mw[w] = bal;
        }
    }
}

// ---------------------------------------------------------------------------
// C = X @ W^T + bias (bf16, m97-style), 128x128 tile, BK=32, glds16 staging.
// MODE 0: z<2 -> bf16 headed [BH][S][DKH] (scaled); z==2 -> TRANSPOSED headed
// kt[bh][d][s] (bias indexed by m-row = output feature, block m/n roles
// swapped so grid stays (32,8,3)). MODE 1: fp32 flat [M][N].
// ---------------------------------------------------------------------------
struct GemmArgs { const short* X[3]; const short* W[3]; const float* B[3];
                  void* C[3]; float scale[3]; };

template <int MODE>
__global__ __launch_bounds__(256) void gemm_bt(GemmArgs a) {
    __shared__ short Ah[128 * 32];
    __shared__ short Bh[128 * 32];
    const int z = blockIdx.z;
    const short* X = a.X[z];
    const short* W = a.W[z];
    const float* bias = a.B[z];
    const float scl = a.scale[z];

    const int t = threadIdx.x, wid = t >> 6, lane = t & 63;
    const int l15 = lane & 15, lq = lane >> 4;
    int m0, n0;
    if (MODE == 0 && z == 2) { m0 = blockIdx.y << 7; n0 = blockIdx.x << 7; }
    else                     { m0 = blockIdx.x << 7; n0 = blockIdx.y << 7; }
    const int wm = (wid >> 1) << 6, wn = (wid & 1) << 6;

    const int kb = (lane & 3) ^ ((lane >> 3) & 3);
    const int r0 = (wid << 5) + (lane >> 2);
    const short* ag0 = X + (size_t)(m0 + r0) * 1024 + (kb << 3);
    const short* ag1 = ag0 + 16 * 1024;
    const short* bg0 = W + (size_t)(n0 + r0) * 1024 + (kb << 3);
    const short* bg1 = bg0 + 16 * 1024;
    short* lA0 = Ah + (wid << 5) * 32;
    short* lA1 = lA0 + 16 * 32;
    short* lB0 = Bh + (wid << 5) * 32;
    short* lB1 = lB0 + 16 * 32;

    const int fpos = (lq ^ ((l15 >> 1) & 3)) << 3;

    f32x4 acc[4][4] = {};

    for (int k0 = 0; k0 < 1024; k0 += 32) {
        __syncthreads();
        glds16(ag0, lA0); glds16(ag1, lA1);
        glds16(bg0, lB0); glds16(bg1, lB1);
        ag0 += 32; ag1 += 32; bg0 += 32; bg1 += 32;
        __syncthreads();

        bf16x8 af[4], bfr[4];
        #pragma unroll
        for (int i = 0; i < 4; ++i)
            af[i] = *(const bf16x8*)&Ah[(wm + i * 16 + l15) * 32 + fpos];
        #pragma unroll
        for (int j = 0; j < 4; ++j)
            bfr[j] = *(const bf16x8*)&Bh[(wn + j * 16 + l15) * 32 + fpos];
        #pragma unroll
        for (int i = 0; i < 4; ++i)
            #pragma unroll
            for (int j = 0; j < 4; ++j)
                acc[i][j] = mfma16(af[i], bfr[j], acc[i][j]);
    }

    if (MODE == 0 && z == 2) {
        // transposed headed write: kt[(b*16+h)*64+d][s], o = m-row feature
        #pragma unroll
        for (int i = 0; i < 4; ++i) {
            #pragma unroll
            for (int r = 0; r < 4; ++r) {
                const int o = m0 + wm + i * 16 + (lq << 2) + r;
                const float bo_ = bias[o];
                const int h = o >> 6, d = o & 63;
                #pragma unroll
                for (int j = 0; j < 4; ++j) {
                    const int n = n0 + wn + j * 16 + l15;
                    const int bb = n >> 11, s = n & 2047;
                    ((short*)a.C[2])[(((size_t)((bb * 16 + h) << 6) + d) << 11) + s] =
                        f2bf(acc[i][j][r] + bo_);
                }
            }
        }
        return;
    }

    #pragma unroll
    for (int j = 0; j < 4; ++j) {
        const int n = n0 + wn + j * 16 + l15;
        const float bn = bias[n];
        #pragma unroll
        for (int i = 0; i < 4; ++i) {
            const int mbase = m0 + wm + i * 16 + (lq << 2);
            #pragma unroll
            for (int r = 0; r < 4; ++r) {
                const float val = (acc[i][j][r] + bn) * scl;
                const int m = mbase + r;
                if (MODE == 0) {
                    const int b = m >> 11, s = m & 2047, h = n >> 6, d = n & 63;
                    ((short*)a.C[z])[((((size_t)(b * 16 + h)) << 11) + s) * 64 + d] = f2bf(val);
                } else {
                    ((float*)a.C[z])[((size_t)m << 10) + n] = val;
                }
            }
        }
    }
}

// ---------------------------------------------------------------------------
// attn4: transposed-S flash attention (reference K/V swap). S^T = V@Q^T via
// 16x16x32 (C-layout col=i=l15, row=j=lq*4+r) -> exp'd scores ARE the
// A-fragments of PV MFMAs (zero P LDS traffic). l via MFMA against all-ones B.
// V and kt staged in LDS with 16B XOR swizzle. j-split z=2; partials merged
// by `combine`. Block: 4 waves x 32 i-rows = 128 rows; grid (16, 32, 2).
// K32 PV/lsum (v6): paf pairs concat into 16x16x32 A-frags.
//
// v8: KVBLK 64 -> 128 via TWO v6-identical 64-j sub-tiles (VsA/KsA, VsB/KsB,
// 32 KiB LDS, still 4 blocks/CU) per barrier pair. v6's ~26% stall sits at
// its 16 barrier/vmcnt-drain events; cross-barrier pipelining failed 4 ways
// (v2/v3 compiler drains on runtime LDS indexing; v7 scratch-spilled: WRITE
// 20->169MB). So instead halve the EVENT COUNT: 8 iterations x {sync, 8
// pipelined glds16, 2 uint4 mask loads, sync, body(A), body(B)}. Code shape
// is v6's byte-identical body (inlined lambda, full unroll, no macros, no
// asm) -> same register/codegen behavior, half the drains.
// ---------------------------------------------------------------------------
__global__ __launch_bounds__(256, 4) void attn4(
    const short* __restrict__ Qh, const short* __restrict__ Vh,
    const short* __restrict__ Kt, const unsigned long long* __restrict__ MW,
    short* __restrict__ Opart, float* __restrict__ lpart)
{
    __shared__ short VsA[64 * 64];   // [j][d], 16B-chunk xor-swizzled
    __shared__ short VsB[64 * 64];
    __shared__ short KsA[64 * 64];   // [d][j], 16B-chunk xor-swizzled
    __shared__ short KsB[64 * 64];

    const int t = threadIdx.x, wid = t >> 6, lane = t & 63;
    const int l15 = lane & 15, lq = lane >> 4;
    const int bh = blockIdx.y, b = bh >> 4;
    const int z = blockIdx.z;
    const int ib = (blockIdx.x << 7) + (wid << 5);
    const int jbase = z << 10;

    // Q B-frags: B[n=i][k=d], rows ib + it*16 + l15
    bf16x8 qf[2][2];
    #pragma unroll
    for (int it = 0; it < 2; ++it) {
        const short* qp = Qh + ((size_t)bh * 2048 + ib + it * 16 + l15) * 64 + (lq << 3);
        qf[it][0] = *(const bf16x8*)qp;
        qf[it][1] = *(const bf16x8*)(qp + 32);
    }

    // staging: each wave stages 16 V-rows and 16 Kt d-rows of EACH sub-tile
    const int sr = lane >> 3, pc = lane & 7;
    const int lc = pc ^ sr;                      // logical 16B chunk
    const int wr = wid << 4;
    const short* vsrc = Vh + (size_t)bh * 131072 + (size_t)(jbase + wr + sr) * 64 + (lc << 3);
    const short* ksrc = Kt + (size_t)bh * 131072 + (size_t)(wr + sr) * 2048 + jbase + (lc << 3);
    short* vdA = VsA + (wr << 6);
    short* vdB = VsB + (wr << 6);
    short* kdA = KsA + (wr << 6);
    short* kdB = KsB + (wr << 6);

    const unsigned long long* mwp0 = MW + ((size_t)b * 2048 + ib + l15) * 32 + (z << 4);
    const unsigned long long* mwp1 = mwp0 + (size_t)16 * 32;

    const int x7 = l15 & 7;
    int voff[2], koff[4];
    #pragma unroll
    for (int p = 0; p < 2; ++p) voff[p] = (((p << 2) + lq) ^ x7) << 3;
    #pragma unroll
    for (int jt = 0; jt < 4; ++jt) {
        const int c8 = (jt << 2) + lq;           // logical 8B chunk
        koff[jt] = (((c8 >> 1) ^ x7) << 3) + ((c8 & 1) << 2);
    }

    f32x4 O[2][4] = {};
    f32x4 lsum[2] = {};
    bf16x8 ones8;
    #pragma unroll
    for (int e = 0; e < 8; ++e) ones8[e] = (short)0x3F80;

    // v6 compute body on one 64-j sub-tile (w0/w1 = mask words for it=0/1)
    auto body = [&](const short* Vb, const short* Kb,
                    unsigned w0x, unsigned w0y, unsigned w1x, unsigned w1y) {
        // V A-frags: A[m=j][k=d]
        bf16x8 vf[4][2];
        #pragma unroll
        for (int jt = 0; jt < 4; ++jt) {
            const short* vp = Vb + (((jt << 4) + l15) << 6);
            vf[jt][0] = *(const bf16x8*)(vp + voff[0]);
            vf[jt][1] = *(const bf16x8*)(vp + voff[1]);
        }

        // S^T tiles -> exp -> packed K32 P A-frags (registers), l via ones-MFMA
        bf16x8 pa[2][2];                         // [it][b2]: concat of jt=2b2,2b2+1
        #pragma unroll
        for (int it = 0; it < 2; ++it) {
            const unsigned wx = it ? w1x : w0x;
            const unsigned wy = it ? w1y : w0y;
            #pragma unroll
            for (int b2 = 0; b2 < 2; ++b2) {
                uint4 uu4;
                unsigned* uw = (unsigned*)&uu4;
                #pragma unroll
                for (int h = 0; h < 2; ++h) {
                    const int jt = (b2 << 1) + h;
                    f32x4 sc = {};
                    sc = mfma16(vf[jt][0], qf[it][0], sc);
                    sc = mfma16(vf[jt][1], qf[it][1], sc);
                    const unsigned w32 = (jt < 2) ? wx : wy;
                    float p[4];
                    #pragma unroll
                    for (int r = 0; r < 4; ++r) {
                        const unsigned bit = (w32 >> (((jt & 1) << 4) + (lq << 2) + r)) & 1u;
                        const float e = EXP2F(sc[r]);
                        p[r] = bit ? e : 0.f;
                    }
                    uw[(h << 1) + 0] = pktrunc(p[0], p[1]);
                    uw[(h << 1) + 1] = pktrunc(p[2], p[3]);
                }
                pa[it][b2] = __builtin_bit_cast(bf16x8, uu4);
                lsum[it] = mfma16(pa[it][b2], ones8, lsum[it]);
            }
        }

        // O += P @ K : B[n=d][k=j] = concat of the two b64 Ks reads per pair
        #pragma unroll
        for (int dt = 0; dt < 4; ++dt) {
            const short* kp = Kb + (((dt << 4) + l15) << 6);
            #pragma unroll
            for (int b2 = 0; b2 < 2; ++b2) {
                const bf16x4 k0 = *(const bf16x4*)(kp + koff[(b2 << 1) + 0]);
                const bf16x4 k1 = *(const bf16x4*)(kp + koff[(b2 << 1) + 1]);
                const bf16x8 kk = cat44(k0, k1);
                O[0][dt] = mfma16(pa[0][b2], kk, O[0][dt]);
                O[1][dt] = mfma16(pa[1][b2], kk, O[1][dt]);
            }
        }
    };

    for (int jc8 = 0; jc8 < 8; ++jc8) {
        __syncthreads();                          // prior reads done before overwrite
        // sub-tile A (j offset 0) and B (j offset 64): 8 pipelined glds16
        glds16(vsrc, vdA);
        glds16(vsrc + 512, vdA + 512);
        glds16(ksrc, kdA);
        glds16(ksrc + 8 * 2048, kdA + 512);
        glds16(vsrc + 4096, vdB);
        glds16(vsrc + 4096 + 512, vdB + 512);
        glds16(ksrc + 64, kdB);
        glds16(ksrc + 64 + 8 * 2048, kdB + 512);
        vsrc += 8192; ksrc += 128;

        // mask words: A and B sub-tiles are adjacent uint2s -> one uint4 each
        const uint4 ma = *(const uint4*)(mwp0 + (jc8 << 1));   // .xy = A, .zw = B (it=0)
        const uint4 mb = *(const uint4*)(mwp1 + (jc8 << 1));   // .xy = A, .zw = B (it=1)
        __syncthreads();                          // drain: both sub-tiles visible

        body(VsA, KsA, ma.x, ma.y, mb.x, mb.y);
        body(VsB, KsB, ma.z, ma.w, mb.z, mb.w);
    }

    // epilogue: rows i = lq*4+r; cols d = dt*16+l15; l duplicated across l15
    const size_t zb = (size_t)((z << 5) + bh) * 2048;
    #pragma unroll
    for (int it = 0; it < 2; ++it) {
        const int rb = ib + (it << 4) + (lq << 2);
        if (l15 == 0) {
            #pragma unroll
            for (int r = 0; r < 4; ++r)
                lpart[zb + rb + r] = lsum[it][r];
        }
        #pragma unroll
        for (int dt = 0; dt < 4; ++dt)
            #pragma unroll
            for (int r = 0; r < 4; ++r)
                Opart[(zb + rb + r) * 64 + (dt << 4) + l15] = f2bf(O[it][dt][r]);
    }
}

// ---------------------------------------------------------------------------
// combine: attr[b][s][h*64+d] = (O0+O1)/(l0+l1), bf16 out
// ---------------------------------------------------------------------------
__global__ __launch_bounds__(256) void combine(const short* __restrict__ Op,
                                               const float* __restrict__ lp,
                                               short* __restrict__ attr) {
    const int idx = blockIdx.x * 256 + threadIdx.x;      // 524288 total
    const int d8 = (idx & 7) << 3;
    const int srow = (idx >> 3) & 2047;
    const int bh = idx >> 14, b = bh >> 4, h = bh & 15;
    const size_t r0 = (size_t)bh * 2048 + srow;
    const size_t r1 = r0 + (size_t)32 * 2048;
    uint4 a = *(const uint4*)(Op + r0 * 64 + d8);
    uint4 c = *(const uint4*)(Op + r1 * 64 + d8);
    const float inv = 1.f / (lp[r0] + lp[r1]);
    const unsigned* au = (const unsigned*)&a;
    const unsigned* cu = (const unsigned*)&c;
    short o[8];
    #pragma unroll
    for (int i = 0; i < 4; ++i) {
        const float a0 = __uint_as_float(au[i] << 16);
        const float a1 = __uint_as_float(au[i] & 0xFFFF0000u);
        const float c0 = __uint_as_float(cu[i] << 16);
        const float c1 = __uint_as_float(cu[i] & 0xFFFF0000u);
        o[2 * i + 0] = f2bf((a0 + c0) * inv);
        o[2 * i + 1] = f2bf((a1 + c1) * inv);
    }
    *(uint4*)&attr[((size_t)b * 2048 + srow) * 1024 + (h << 6) + d8] = *(uint4*)o;
}

// ---------------------------------------------------------------------------
extern "C" void kernel_launch(void* const* d_in, const int* in_sizes, int n_in,
                              void* d_out, int out_size, void* d_ws, size_t ws_size,
                              hipStream_t stream) {
    const float* value = (const float*)d_in[0];
    const float* key   = (const float*)d_in[1];
    const float* query = (const float*)d_in[2];
    const int*   mask  = (const int*)d_in[3];
    const float* bv = (const float*)d_in[5];
    const float* bk = (const float*)d_in[7];
    const float* bq = (const float*)d_in[9];
    const float* bo = (const float*)d_in[11];
    float* out = (float*)d_out;

    const size_t M1 = (size_t)1 << 20, M4 = (size_t)1 << 22;
    short* ws = (short*)d_ws;
    short* Xq = ws;                       // reused as attr after proj
    short* Xk = ws + M4;                  // reused as Opart after proj (2*M4)
    short* Xv = ws + 2 * M4;
    short* Wc0 = ws + 3 * M4;             // reused as lpart after proj
    short* Wc1 = Wc0 + M1;
    short* Wc2 = Wc1 + M1;
    short* Wc3 = Wc2 + M1;
    short* qh = ws + 4 * M4;
    short* kt = ws + 5 * M4;
    short* vh = ws + 6 * M4;
    unsigned long long* maskw = (unsigned long long*)(ws + 7 * M4);
    short* attr = Xq;
    short* Opart = Xk;
    float* lpart = (float*)Wc0;

    CvtArgs cv;
    cv.src[0] = query; cv.dst[0] = Xq;
    cv.src[1] = key;   cv.dst[1] = Xk;
    cv.src[2] = value; cv.dst[2] = Xv;
    cv.src[3] = (const float*)d_in[8];  cv.dst[3] = Wc0;  // Wq
    cv.src[4] = (const float*)d_in[6];  cv.dst[4] = Wc1;  // Wk
    cv.src[5] = (const float*)d_in[4];  cv.dst[5] = Wc2;  // Wv
    cv.src[6] = (const float*)d_in[10]; cv.dst[6] = Wc3;  // Wo
    prep<<<10240, 256, 0, stream>>>(cv, mask, maskw);

    GemmArgs g1;
    g1.X[0] = Xq;  g1.W[0] = Wc0; g1.B[0] = bq; g1.C[0] = qh; g1.scale[0] = QSCALE;
    g1.X[1] = Xv;  g1.W[1] = Wc2; g1.B[1] = bv; g1.C[1] = vh; g1.scale[1] = 1.f;
    g1.X[2] = Wc1; g1.W[2] = Xk;  g1.B[2] = bk; g1.C[2] = kt; g1.scale[2] = 1.f;  // transposed K
    gemm_bt<0><<<dim3(32, 8, 3), 256, 0, stream>>>(g1);

    attn4<<<dim3(16, 32, 2), 256, 0, stream>>>(qh, vh, kt, maskw, Opart, lpart);

    combine<<<2048, 256, 0, stream>>>(Opart, lpart, attr);

    GemmArgs g2;
    g2.X[0] = attr; g2.W[0] = Wc3; g2.B[0] = bo; g2.C[0] = out; g2.scale[0] = 1.f;
    g2.X[1] = attr; g2.W[1] = Wc3; g2.B[1] = bo; g2.C[1] = out; g2.scale[1] = 1.f;
    g2.X[2] = attr; g2.W[2] = Wc3; g2.B[2] = bo; g2.C[2] = out; g2.scale[2] = 1.f;
    gemm_bt<1><<<dim3(32, 8, 1), 256, 0, stream>>>(g2);
}

// Round 10
// 268.844 us; speedup vs baseline: 1.2675x; 1.0469x over previous
//
#include <hip/hip_runtime.h>

#define S_LEN 2048
#define DMODEL 1024
#define NHEADS 16
#define DKH 64

typedef __attribute__((ext_vector_type(8))) short bf16x8;
typedef __attribute__((ext_vector_type(4))) short bf16x4;
typedef __attribute__((ext_vector_type(4))) float f32x4;

#if __has_builtin(__builtin_amdgcn_exp2f)
#define EXP2F(x) __builtin_amdgcn_exp2f(x)
#define QSCALE (0.125f * 1.44269504f)
#else
#define EXP2F(x) __expf(x)
#define QSCALE 0.125f
#endif

static __device__ __forceinline__ short f2bf(float f) {
    unsigned b = __float_as_uint(f);
    b = (b + 0x7FFFu + ((b >> 16) & 1u)) >> 16;   // RNE
    return (short)b;
}

// pack truncated-bf16 of (lo,hi) into one u32
static __device__ __forceinline__ unsigned pktrunc(float lo, float hi) {
#if __has_builtin(__builtin_amdgcn_perm)
    return __builtin_amdgcn_perm(__float_as_uint(hi), __float_as_uint(lo), 0x07060302u);
#else
    return (__float_as_uint(lo) >> 16) | (__float_as_uint(hi) & 0xFFFF0000u);
#endif
}

static __device__ __forceinline__ f32x4 mfma16(bf16x8 a, bf16x8 b, f32x4 c) {
    return __builtin_amdgcn_mfma_f32_16x16x32_bf16(a, b, c, 0, 0, 0);
}

static __device__ __forceinline__ bf16x8 cat44(bf16x4 a, bf16x4 b) {
    bf16x8 r;
    r[0] = a[0]; r[1] = a[1]; r[2] = a[2]; r[3] = a[3];
    r[4] = b[0]; r[5] = b[1]; r[6] = b[2]; r[7] = b[3];
    return r;
}

static __device__ __forceinline__ void glds16(const short* g, short* l) {
    __builtin_amdgcn_global_load_lds(
        (const __attribute__((address_space(1))) void*)g,
        (__attribute__((address_space(3))) void*)l, 16, 0, 0);
}

// ---------------------------------------------------------------------------
// prep: fused fp32->bf16 convert (blocks 0..8191) + mask bit-pack (2048 blocks)
// ---------------------------------------------------------------------------
struct CvtArgs { const float* src[7]; short* dst[7]; };

__global__ __launch_bounds__(256) void prep(CvtArgs a, const int* __restrict__ mask,
                                            unsigned long long* __restrict__ mw) {
    if (blockIdx.x < 8192) {
        const size_t i8 = ((size_t)blockIdx.x * 256 + threadIdx.x) * 8;
        int seg; size_t off;
        if (i8 < ((size_t)12 << 20)) { seg = (int)(i8 >> 22); off = i8 & ((1u << 22) - 1); }
        else { size_t r = i8 - ((size_t)12 << 20); seg = 3 + (int)(r >> 20); off = r & ((1u << 20) - 1); }
        const float* s = a.src[seg] + off;
        float4 x0 = *(const float4*)s, x1 = *(const float4*)(s + 4);
        short o[8];
        o[0] = f2bf(x0.x); o[1] = f2bf(x0.y); o[2] = f2bf(x0.z); o[3] = f2bf(x0.w);
        o[4] = f2bf(x1.x); o[5] = f2bf(x1.y); o[6] = f2bf(x1.z); o[7] = f2bf(x1.w);
        *(uint4*)(a.dst[seg] + off) = *(uint4*)o;
    } else {
        const int wv = ((blockIdx.x - 8192) << 2) + (threadIdx.x >> 6);
        const int lane = threadIdx.x & 63;
        const size_t base = (size_t)wv << 4;
        #pragma unroll 4
        for (int it = 0; it < 16; ++it) {
            const size_t w = base + it;
            const int m = mask[(w << 6) + lane];
            unsigned long long bal = __ballot(m != 0);
            if (lane == 0) mw[w] = bal;
        }
    }
}

// ---------------------------------------------------------------------------
// C = X @ W^T + bias (bf16, m97-style), 128x128 tile, BK=32, glds16 staging.
// MODE 0: z<2 -> bf16 headed [BH][S][DKH] (scaled); z==2 -> TRANSPOSED headed
// kt[bh][d][s] (bias indexed by m-row = output feature, block m/n roles
// swapped so grid stays (32,8,3)). MODE 1: fp32 flat [M][N].
// v9: XCD-cluster swizzle (T1). Dispatch round-robins wgid%8 across XCDs;
// remap so each XCD owns a 4x8 tile patch per z (shares 4 X-panels + the
// whole W slice in its private L2) instead of scattering rows across L2s.
// ---------------------------------------------------------------------------
struct GemmArgs { const short* X[3]; const short* W[3]; const float* B[3];
                  void* C[3]; float scale[3]; };

template <int MODE>
__global__ __launch_bounds__(256) void gemm_bt(GemmArgs a) {
    __shared__ short Ah[128 * 32];
    __shared__ short Bh[128 * 32];
    const int z = blockIdx.z;
    const short* X = a.X[z];
    const short* W = a.W[z];
    const float* bias = a.B[z];
    const float scl = a.scale[z];

    const int t = threadIdx.x, wid = t >> 6, lane = t & 63;
    const int l15 = lane & 15, lq = lane >> 4;

    // XCD-cluster: lid in [0,256) per z; xcd = lid&7 (256%8==0 so z-invariant)
    const int lid = blockIdx.x + (blockIdx.y << 5);
    const int vm = ((lid & 7) << 2) + ((lid >> 3) & 3);   // [0,32)
    const int vn = lid >> 5;                              // [0,8)

    int m0, n0;
    if (MODE == 0 && z == 2) { m0 = vn << 7; n0 = vm << 7; }
    else                     { m0 = vm << 7; n0 = vn << 7; }
    const int wm = (wid >> 1) << 6, wn = (wid & 1) << 6;

    const int kb = (lane & 3) ^ ((lane >> 3) & 3);
    const int r0 = (wid << 5) + (lane >> 2);
    const short* ag0 = X + (size_t)(m0 + r0) * 1024 + (kb << 3);
    const short* ag1 = ag0 + 16 * 1024;
    const short* bg0 = W + (size_t)(n0 + r0) * 1024 + (kb << 3);
    const short* bg1 = bg0 + 16 * 1024;
    short* lA0 = Ah + (wid << 5) * 32;
    short* lA1 = lA0 + 16 * 32;
    short* lB0 = Bh + (wid << 5) * 32;
    short* lB1 = lB0 + 16 * 32;

    const int fpos = (lq ^ ((l15 >> 1) & 3)) << 3;

    f32x4 acc[4][4] = {};

    for (int k0 = 0; k0 < 1024; k0 += 32) {
        __syncthreads();
        glds16(ag0, lA0); glds16(ag1, lA1);
        glds16(bg0, lB0); glds16(bg1, lB1);
        ag0 += 32; ag1 += 32; bg0 += 32; bg1 += 32;
        __syncthreads();

        bf16x8 af[4], bfr[4];
        #pragma unroll
        for (int i = 0; i < 4; ++i)
            af[i] = *(const bf16x8*)&Ah[(wm + i * 16 + l15) * 32 + fpos];
        #pragma unroll
        for (int j = 0; j < 4; ++j)
            bfr[j] = *(const bf16x8*)&Bh[(wn + j * 16 + l15) * 32 + fpos];
        #pragma unroll
        for (int i = 0; i < 4; ++i)
            #pragma unroll
            for (int j = 0; j < 4; ++j)
                acc[i][j] = mfma16(af[i], bfr[j], acc[i][j]);
    }

    if (MODE == 0 && z == 2) {
        // transposed headed write: kt[(b*16+h)*64+d][s], o = m-row feature
        #pragma unroll
        for (int i = 0; i < 4; ++i) {
            #pragma unroll
            for (int r = 0; r < 4; ++r) {
                const int o = m0 + wm + i * 16 + (lq << 2) + r;
                const float bo_ = bias[o];
                const int h = o >> 6, d = o & 63;
                #pragma unroll
                for (int j = 0; j < 4; ++j) {
                    const int n = n0 + wn + j * 16 + l15;
                    const int bb = n >> 11, s = n & 2047;
                    ((short*)a.C[2])[(((size_t)((bb * 16 + h) << 6) + d) << 11) + s] =
                        f2bf(acc[i][j][r] + bo_);
                }
            }
        }
        return;
    }

    #pragma unroll
    for (int j = 0; j < 4; ++j) {
        const int n = n0 + wn + j * 16 + l15;
        const float bn = bias[n];
        #pragma unroll
        for (int i = 0; i < 4; ++i) {
            const int mbase = m0 + wm + i * 16 + (lq << 2);
            #pragma unroll
            for (int r = 0; r < 4; ++r) {
                const float val = (acc[i][j][r] + bn) * scl;
                const int m = mbase + r;
                if (MODE == 0) {
                    const int b = m >> 11, s = m & 2047, h = n >> 6, d = n & 63;
                    ((short*)a.C[z])[((((size_t)(b * 16 + h)) << 11) + s) * 64 + d] = f2bf(val);
                } else {
                    ((float*)a.C[z])[((size_t)m << 10) + n] = val;
                }
            }
        }
    }
}

// ---------------------------------------------------------------------------
// attn4: transposed-S flash attention (reference K/V swap). S^T = V@Q^T via
// 16x16x32 (C-layout col=i=l15, row=j=lq*4+r) -> exp'd scores ARE the
// A-fragments of PV MFMAs (zero P LDS traffic). l via MFMA against all-ones B.
// V and kt staged in LDS with 16B XOR swizzle. j-split z=2; partials merged
// by `combine`. Block: 4 waves x 32 i-rows = 128 rows. K32 PV/lsum (v6).
//
// v9 = v6 inner loop byte-identical (every structural variant v2-v8 inflated
// FETCH and lost) + XCD-cluster block mapping: 1-D grid of 1024; xcd=lid&7;
// all 16 i-blocks of one (bh,z) land on ONE XCD (8 groups/XCD x 512KB
// (V+K+Q) = 4MB = one L2). v6's round-robin placed 2 blocks/XCD per group ->
// every XCD refetched the group's 256KB V/K (FETCH 72MB vs ~26MB ideal);
// the per-jc barrier drain then waits on HBM/L3 (~900cy) instead of L2
// (~200cy) — that latency IS the measured ~26% stall.
// ---------------------------------------------------------------------------
__global__ __launch_bounds__(256, 4) void attn4(
    const short* __restrict__ Qh, const short* __restrict__ Vh,
    const short* __restrict__ Kt, const unsigned long long* __restrict__ MW,
    short* __restrict__ Opart, float* __restrict__ lpart)
{
    __shared__ short Vs[64 * 64];    // [j][d], 16B-chunk xor-swizzled
    __shared__ short Ks[64 * 64];    // [d][j], 16B-chunk xor-swizzled

    const int t = threadIdx.x, wid = t >> 6, lane = t & 63;
    const int l15 = lane & 15, lq = lane >> 4;

    // XCD-cluster mapping: lid in [0,1024); xcd = lid&7; 8 (bh,z)-groups/XCD
    const int lid = blockIdx.x;
    const int slot = lid >> 3;                        // [0,128)
    const int g = ((lid & 7) << 3) + (slot >> 4);     // [0,64) group id
    const int bh = g & 31, b = bh >> 4;
    const int z = g >> 5;
    const int ib = ((slot & 15) << 7) + (wid << 5);
    const int jbase = z << 10;

    // Q B-frags: B[n=i][k=d], rows ib + it*16 + l15
    bf16x8 qf[2][2];
    #pragma unroll
    for (int it = 0; it < 2; ++it) {
        const short* qp = Qh + ((size_t)bh * 2048 + ib + it * 16 + l15) * 64 + (lq << 3);
        qf[it][0] = *(const bf16x8*)qp;
        qf[it][1] = *(const bf16x8*)(qp + 32);
    }

    // staging: each wave stages 16 rows of V and 16 d-rows of Kt
    const int sr = lane >> 3, pc = lane & 7;
    const int lc = pc ^ sr;                      // logical 16B chunk
    const int wr = wid << 4;
    const short* vsrc = Vh + (size_t)bh * 131072 + (size_t)(jbase + wr + sr) * 64 + (lc << 3);
    const short* ksrc = Kt + (size_t)bh * 131072 + (size_t)(wr + sr) * 2048 + jbase + (lc << 3);
    short* vdst = Vs + (wr << 6);
    short* kdst = Ks + (wr << 6);

    const unsigned long long* mwp0 = MW + ((size_t)b * 2048 + ib + l15) * 32 + (z << 4);
    const unsigned long long* mwp1 = mwp0 + (size_t)16 * 32;

    const int x7 = l15 & 7;
    int voff[2], koff[4];
    #pragma unroll
    for (int p = 0; p < 2; ++p) voff[p] = (((p << 2) + lq) ^ x7) << 3;
    #pragma unroll
    for (int jt = 0; jt < 4; ++jt) {
        const int c8 = (jt << 2) + lq;           // logical 8B chunk
        koff[jt] = (((c8 >> 1) ^ x7) << 3) + ((c8 & 1) << 2);
    }

    f32x4 O[2][4] = {};
    f32x4 lsum[2] = {};
    bf16x8 ones8;
    #pragma unroll
    for (int e = 0; e < 8; ++e) ones8[e] = (short)0x3F80;

    for (int jc = 0; jc < 16; ++jc) {
        __syncthreads();
        glds16(vsrc, vdst);
        glds16(vsrc + 512, vdst + 512);
        glds16(ksrc, kdst);
        glds16(ksrc + 8 * 2048, kdst + 512);
        vsrc += 4096; ksrc += 64;

        uint2 mword[2];
        mword[0] = *(const uint2*)(mwp0 + jc);
        mword[1] = *(const uint2*)(mwp1 + jc);
        __syncthreads();

        // V A-frags: A[m=j][k=d]
        bf16x8 vf[4][2];
        #pragma unroll
        for (int jt = 0; jt < 4; ++jt) {
            const short* vp = &Vs[((jt << 4) + l15) << 6];
            vf[jt][0] = *(const bf16x8*)(vp + voff[0]);
            vf[jt][1] = *(const bf16x8*)(vp + voff[1]);
        }

        // S^T tiles -> exp -> packed K32 P A-frags (registers), l via ones-MFMA
        bf16x8 pa[2][2];                         // [it][b2]: concat of jt=2b2,2b2+1
        #pragma unroll
        for (int it = 0; it < 2; ++it) {
            const unsigned wx = mword[it].x, wy = mword[it].y;
            #pragma unroll
            for (int b2 = 0; b2 < 2; ++b2) {
                uint4 uu4;
                unsigned* uw = (unsigned*)&uu4;
                #pragma unroll
                for (int h = 0; h < 2; ++h) {
                    const int jt = (b2 << 1) + h;
                    f32x4 sc = {};
                    sc = mfma16(vf[jt][0], qf[it][0], sc);
                    sc = mfma16(vf[jt][1], qf[it][1], sc);
                    const unsigned w32 = (jt < 2) ? wx : wy;
                    float p[4];
                    #pragma unroll
                    for (int r = 0; r < 4; ++r) {
                        const unsigned bit = (w32 >> (((jt & 1) << 4) + (lq << 2) + r)) & 1u;
                        const float e = EXP2F(sc[r]);
                        p[r] = bit ? e : 0.f;
                    }
                    uw[(h << 1) + 0] = pktrunc(p[0], p[1]);
                    uw[(h << 1) + 1] = pktrunc(p[2], p[3]);
                }
                pa[it][b2] = __builtin_bit_cast(bf16x8, uu4);
                lsum[it] = mfma16(pa[it][b2], ones8, lsum[it]);
            }
        }

        // O += P @ K : B[n=d][k=j] = concat of the two b64 Ks reads per pair
        #pragma unroll
        for (int dt = 0; dt < 4; ++dt) {
            const short* kp = &Ks[((dt << 4) + l15) << 6];
            #pragma unroll
            for (int b2 = 0; b2 < 2; ++b2) {
                const bf16x4 k0 = *(const bf16x4*)(kp + koff[(b2 << 1) + 0]);
                const bf16x4 k1 = *(const bf16x4*)(kp + koff[(b2 << 1) + 1]);
                const bf16x8 kk = cat44(k0, k1);
                O[0][dt] = mfma16(pa[0][b2], kk, O[0][dt]);
                O[1][dt] = mfma16(pa[1][b2], kk, O[1][dt]);
            }
        }
    }

    // epilogue: rows i = lq*4+r; cols d = dt*16+l15; l duplicated across l15
    const size_t zb = (size_t)((z << 5) + bh) * 2048;
    #pragma unroll
    for (int it = 0; it < 2; ++it) {
        const int rb = ib + (it << 4) + (lq << 2);
        if (l15 == 0) {
            #pragma unroll
            for (int r = 0; r < 4; ++r)
                lpart[zb + rb + r] = lsum[it][r];
        }
        #pragma unroll
        for (int dt = 0; dt < 4; ++dt)
            #pragma unroll
            for (int r = 0; r < 4; ++r)
                Opart[(zb + rb + r) * 64 + (dt << 4) + l15] = f2bf(O[it][dt][r]);
    }
}

// ---------------------------------------------------------------------------
// combine: attr[b][s][h*64+d] = (O0+O1)/(l0+l1), bf16 out
// ---------------------------------------------------------------------------
__global__ __launch_bounds__(256) void combine(const short* __restrict__ Op,
                                               const float* __restrict__ lp,
                                               short* __restrict__ attr) {
    const int idx = blockIdx.x * 256 + threadIdx.x;      // 524288 total
    const int d8 = (idx & 7) << 3;
    const int srow = (idx >> 3) & 2047;
    const int bh = idx >> 14, b = bh >> 4, h = bh & 15;
    const size_t r0 = (size_t)bh * 2048 + srow;
    const size_t r1 = r0 + (size_t)32 * 2048;
    uint4 a = *(const uint4*)(Op + r0 * 64 + d8);
    uint4 c = *(const uint4*)(Op + r1 * 64 + d8);
    const float inv = 1.f / (lp[r0] + lp[r1]);
    const unsigned* au = (const unsigned*)&a;
    const unsigned* cu = (const unsigned*)&c;
    short o[8];
    #pragma unroll
    for (int i = 0; i < 4; ++i) {
        const float a0 = __uint_as_float(au[i] << 16);
        const float a1 = __uint_as_float(au[i] & 0xFFFF0000u);
        const float c0 = __uint_as_float(cu[i] << 16);
        const float c1 = __uint_as_float(cu[i] & 0xFFFF0000u);
        o[2 * i + 0] = f2bf((a0 + c0) * inv);
        o[2 * i + 1] = f2bf((a1 + c1) * inv);
    }
    *(uint4*)&attr[((size_t)b * 2048 + srow) * 1024 + (h << 6) + d8] = *(uint4*)o;
}

// ---------------------------------------------------------------------------
extern "C" void kernel_launch(void* const* d_in, const int* in_sizes, int n_in,
                              void* d_out, int out_size, void* d_ws, size_t ws_size,
                              hipStream_t stream) {
    const float* value = (const float*)d_in[0];
    const float* key   = (const float*)d_in[1];
    const float* query = (const float*)d_in[2];
    const int*   mask  = (const int*)d_in[3];
    const float* bv = (const float*)d_in[5];
    const float* bk = (const float*)d_in[7];
    const float* bq = (const float*)d_in[9];
    const float* bo = (const float*)d_in[11];
    float* out = (float*)d_out;

    const size_t M1 = (size_t)1 << 20, M4 = (size_t)1 << 22;
    short* ws = (short*)d_ws;
    short* Xq = ws;                       // reused as attr after proj
    short* Xk = ws + M4;                  // reused as Opart after proj (2*M4)
    short* Xv = ws + 2 * M4;
    short* Wc0 = ws + 3 * M4;             // reused as lpart after proj
    short* Wc1 = Wc0 + M1;
    short* Wc2 = Wc1 + M1;
    short* Wc3 = Wc2 + M1;
    short* qh = ws + 4 * M4;
    short* kt = ws + 5 * M4;
    short* vh = ws + 6 * M4;
    unsigned long long* maskw = (unsigned long long*)(ws + 7 * M4);
    short* attr = Xq;
    short* Opart = Xk;
    float* lpart = (float*)Wc0;

    CvtArgs cv;
    cv.src[0] = query; cv.dst[0] = Xq;
    cv.src[1] = key;   cv.dst[1] = Xk;
    cv.src[2] = value; cv.dst[2] = Xv;
    cv.src[3] = (const float*)d_in[8];  cv.dst[3] = Wc0;  // Wq
    cv.src[4] = (const float*)d_in[6];  cv.dst[4] = Wc1;  // Wk
    cv.src[5] = (const float*)d_in[4];  cv.dst[5] = Wc2;  // Wv
    cv.src[6] = (const float*)d_in[10]; cv.dst[6] = Wc3;  // Wo
    prep<<<10240, 256, 0, stream>>>(cv, mask, maskw);

    GemmArgs g1;
    g1.X[0] = Xq;  g1.W[0] = Wc0; g1.B[0] = bq; g1.C[0] = qh; g1.scale[0] = QSCALE;
    g1.X[1] = Xv;  g1.W[1] = Wc2; g1.B[1] = bv; g1.C[1] = vh; g1.scale[1] = 1.f;
    g1.X[2] = Wc1; g1.W[2] = Xk;  g1.B[2] = bk; g1.C[2] = kt; g1.scale[2] = 1.f;  // transposed K
    gemm_bt<0><<<dim3(32, 8, 3), 256, 0, stream>>>(g1);

    attn4<<<dim3(1024), 256, 0, stream>>>(qh, vh, kt, maskw, Opart, lpart);

    combine<<<2048, 256, 0, stream>>>(Opart, lpart, attr);

    GemmArgs g2;
    g2.X[0] = attr; g2.W[0] = Wc3; g2.B[0] = bo; g2.C[0] = out; g2.scale[0] = 1.f;
    g2.X[1] = attr; g2.W[1] = Wc3; g2.B[1] = bo; g2.C[1] = out; g2.scale[1] = 1.f;
    g2.X[2] = attr; g2.W[2] = Wc3; g2.B[2] = bo; g2.C[2] = out; g2.scale[2] = 1.f;
    gemm_bt<1><<<dim3(32, 8, 1), 256, 0, stream>>>(g2);
}

// Round 11
// 268.168 us; speedup vs baseline: 1.2707x; 1.0025x over previous
//
#include <hip/hip_runtime.h>

#define S_LEN 2048
#define DMODEL 1024
#define NHEADS 16
#define DKH 64

typedef __attribute__((ext_vector_type(8))) short bf16x8;
typedef __attribute__((ext_vector_type(4))) short bf16x4;
typedef __attribute__((ext_vector_type(4))) float f32x4;

#if __has_builtin(__builtin_amdgcn_exp2f)
#define EXP2F(x) __builtin_amdgcn_exp2f(x)
#define QSCALE (0.125f * 1.44269504f)
#else
#define EXP2F(x) __expf(x)
#define QSCALE 0.125f
#endif

static __device__ __forceinline__ short f2bf(float f) {
    unsigned b = __float_as_uint(f);
    b = (b + 0x7FFFu + ((b >> 16) & 1u)) >> 16;   // RNE
    return (short)b;
}

// pack truncated-bf16 of (lo,hi) into one u32
static __device__ __forceinline__ unsigned pktrunc(float lo, float hi) {
#if __has_builtin(__builtin_amdgcn_perm)
    return __builtin_amdgcn_perm(__float_as_uint(hi), __float_as_uint(lo), 0x07060302u);
#else
    return (__float_as_uint(lo) >> 16) | (__float_as_uint(hi) & 0xFFFF0000u);
#endif
}

static __device__ __forceinline__ f32x4 mfma16(bf16x8 a, bf16x8 b, f32x4 c) {
    return __builtin_amdgcn_mfma_f32_16x16x32_bf16(a, b, c, 0, 0, 0);
}

static __device__ __forceinline__ bf16x8 cat44(bf16x4 a, bf16x4 b) {
    bf16x8 r;
    r[0] = a[0]; r[1] = a[1]; r[2] = a[2]; r[3] = a[3];
    r[4] = b[0]; r[5] = b[1]; r[6] = b[2]; r[7] = b[3];
    return r;
}

static __device__ __forceinline__ void glds16(const short* g, short* l) {
    __builtin_amdgcn_global_load_lds(
        (const __attribute__((address_space(1))) void*)g,
        (__attribute__((address_space(3))) void*)l, 16, 0, 0);
}

// ---------------------------------------------------------------------------
// prep: fused fp32->bf16 convert (blocks 0..8191) + mask bit-pack (2048 blocks)
// ---------------------------------------------------------------------------
struct CvtArgs { const float* src[7]; short* dst[7]; };

__global__ __launch_bounds__(256) void prep(CvtArgs a, const int* __restrict__ mask,
                                            unsigned long long* __restrict__ mw) {
    if (blockIdx.x < 8192) {
        const size_t i8 = ((size_t)blockIdx.x * 256 + threadIdx.x) * 8;
        int seg; size_t off;
        if (i8 < ((size_t)12 << 20)) { seg = (int)(i8 >> 22); off = i8 & ((1u << 22) - 1); }
        else { size_t r = i8 - ((size_t)12 << 20); seg = 3 + (int)(r >> 20); off = r & ((1u << 20) - 1); }
        const float* s = a.src[seg] + off;
        float4 x0 = *(const float4*)s, x1 = *(const float4*)(s + 4);
        short o[8];
        o[0] = f2bf(x0.x); o[1] = f2bf(x0.y); o[2] = f2bf(x0.z); o[3] = f2bf(x0.w);
        o[4] = f2bf(x1.x); o[5] = f2bf(x1.y); o[6] = f2bf(x1.z); o[7] = f2bf(x1.w);
        *(uint4*)(a.dst[seg] + off) = *(uint4*)o;
    } else {
        const int wv = ((blockIdx.x - 8192) << 2) + (threadIdx.x >> 6);
        const int lane = threadIdx.x & 63;
        const size_t base = (size_t)wv << 4;
        #pragma unroll 4
        for (int it = 0; it < 16; ++it) {
            const size_t w = base + it;
            const int m = mask[(w << 6) + lane];
            unsigned long long bal = __ballot(m != 0);
            if (lane == 0) mw[w] = bal;
        }
    }
}

// ---------------------------------------------------------------------------
// C = X @ W^T + bias (bf16, m97-style), 128x128 tile, BK=32, glds16 staging.
// MODE 0: z<2 -> bf16 headed [BH][S][DKH] (scaled); z==2 -> TRANSPOSED headed
// kt[bh][d][s]. XCD-cluster swizzle: each XCD owns a 4x8 tile patch per z.
// ---------------------------------------------------------------------------
struct GemmArgs { const short* X[3]; const short* W[3]; const float* B[3];
                  void* C[3]; float scale[3]; };

template <int MODE>
__global__ __launch_bounds__(256) void gemm_bt(GemmArgs a) {
    __shared__ short Ah[128 * 32];
    __shared__ short Bh[128 * 32];
    const int z = blockIdx.z;
    const short* X = a.X[z];
    const short* W = a.W[z];
    const float* bias = a.B[z];
    const float scl = a.scale[z];

    const int t = threadIdx.x, wid = t >> 6, lane = t & 63;
    const int l15 = lane & 15, lq = lane >> 4;

    // XCD-cluster: lid in [0,256) per z; xcd = lid&7 (256%8==0 so z-invariant)
    const int lid = blockIdx.x + (blockIdx.y << 5);
    const int vm = ((lid & 7) << 2) + ((lid >> 3) & 3);   // [0,32)
    const int vn = lid >> 5;                              // [0,8)

    int m0, n0;
    if (MODE == 0 && z == 2) { m0 = vn << 7; n0 = vm << 7; }
    else                     { m0 = vm << 7; n0 = vn << 7; }
    const int wm = (wid >> 1) << 6, wn = (wid & 1) << 6;

    const int kb = (lane & 3) ^ ((lane >> 3) & 3);
    const int r0 = (wid << 5) + (lane >> 2);
    const short* ag0 = X + (size_t)(m0 + r0) * 1024 + (kb << 3);
    const short* ag1 = ag0 + 16 * 1024;
    const short* bg0 = W + (size_t)(n0 + r0) * 1024 + (kb << 3);
    const short* bg1 = bg0 + 16 * 1024;
    short* lA0 = Ah + (wid << 5) * 32;
    short* lA1 = lA0 + 16 * 32;
    short* lB0 = Bh + (wid << 5) * 32;
    short* lB1 = lB0 + 16 * 32;

    const int fpos = (lq ^ ((l15 >> 1) & 3)) << 3;

    f32x4 acc[4][4] = {};

    for (int k0 = 0; k0 < 1024; k0 += 32) {
        __syncthreads();
        glds16(ag0, lA0); glds16(ag1, lA1);
        glds16(bg0, lB0); glds16(bg1, lB1);
        ag0 += 32; ag1 += 32; bg0 += 32; bg1 += 32;
        __syncthreads();

        bf16x8 af[4], bfr[4];
        #pragma unroll
        for (int i = 0; i < 4; ++i)
            af[i] = *(const bf16x8*)&Ah[(wm + i * 16 + l15) * 32 + fpos];
        #pragma unroll
        for (int j = 0; j < 4; ++j)
            bfr[j] = *(const bf16x8*)&Bh[(wn + j * 16 + l15) * 32 + fpos];
        #pragma unroll
        for (int i = 0; i < 4; ++i)
            #pragma unroll
            for (int j = 0; j < 4; ++j)
                acc[i][j] = mfma16(af[i], bfr[j], acc[i][j]);
    }

    if (MODE == 0 && z == 2) {
        // transposed headed write: kt[(b*16+h)*64+d][s], o = m-row feature
        #pragma unroll
        for (int i = 0; i < 4; ++i) {
            #pragma unroll
            for (int r = 0; r < 4; ++r) {
                const int o = m0 + wm + i * 16 + (lq << 2) + r;
                const float bo_ = bias[o];
                const int h = o >> 6, d = o & 63;
                #pragma unroll
                for (int j = 0; j < 4; ++j) {
                    const int n = n0 + wn + j * 16 + l15;
                    const int bb = n >> 11, s = n & 2047;
                    ((short*)a.C[2])[(((size_t)((bb * 16 + h) << 6) + d) << 11) + s] =
                        f2bf(acc[i][j][r] + bo_);
                }
            }
        }
        return;
    }

    #pragma unroll
    for (int j = 0; j < 4; ++j) {
        const int n = n0 + wn + j * 16 + l15;
        const float bn = bias[n];
        #pragma unroll
        for (int i = 0; i < 4; ++i) {
            const int mbase = m0 + wm + i * 16 + (lq << 2);
            #pragma unroll
            for (int r = 0; r < 4; ++r) {
                const float val = (acc[i][j][r] + bn) * scl;
                const int m = mbase + r;
                if (MODE == 0) {
                    const int b = m >> 11, s = m & 2047, h = n >> 6, d = n & 63;
                    ((short*)a.C[z])[((((size_t)(b * 16 + h)) << 11) + s) * 64 + d] = f2bf(val);
                } else {
                    ((float*)a.C[z])[((size_t)m << 10) + n] = val;
                }
            }
        }
    }
}

// ---------------------------------------------------------------------------
// gemm1_64: out = attr @ Wo^T + bo, fp32 out. 128x64 tiles -> grid (32,16) =
// 512 blocks = 2 blocks/CU (the old 128x128 MODE-1 ran 256 blocks = 1/CU =
// 1 wave/SIMD: every per-K-step vmcnt(0) drain fully exposed, zero overlap;
// m114 overlap needs >=2 co-resident blocks). Waves 2x2 over (64M x 32N),
// acc 4x2; A staging identical to gemm_bt; B = one 16-row glds16 per wave
// (same lane->row/kb mapping). XCD swizzle: per-XCD set = 4 A-patches (1MB)
// + all of Wo (2MB) < 4MB L2.
// ---------------------------------------------------------------------------
__global__ __launch_bounds__(256) void gemm1_64(const short* __restrict__ X,
                                                const short* __restrict__ W,
                                                const float* __restrict__ bias,
                                                float* __restrict__ C) {
    __shared__ short Ah[128 * 32];
    __shared__ short Bh[64 * 32];

    const int t = threadIdx.x, wid = t >> 6, lane = t & 63;
    const int l15 = lane & 15, lq = lane >> 4;

    const int lid = blockIdx.x + (blockIdx.y << 5);       // [0,512)
    const int vm = ((lid & 7) << 2) + ((lid >> 3) & 3);   // [0,32)
    const int vn = lid >> 5;                              // [0,16)
    const int m0 = vm << 7, n0 = vn << 6;
    const int wm = (wid >> 1) << 6, wn = (wid & 1) << 5;

    const int kb = (lane & 3) ^ ((lane >> 3) & 3);
    const int r0 = (wid << 5) + (lane >> 2);
    const short* ag0 = X + (size_t)(m0 + r0) * 1024 + (kb << 3);
    const short* ag1 = ag0 + 16 * 1024;
    const short* bg  = W + (size_t)(n0 + (wid << 4) + (lane >> 2)) * 1024 + (kb << 3);
    short* lA0 = Ah + (wid << 5) * 32;
    short* lA1 = lA0 + 16 * 32;
    short* lB  = Bh + (wid << 4) * 32;

    const int fpos = (lq ^ ((l15 >> 1) & 3)) << 3;

    f32x4 acc[4][2] = {};

    for (int k0 = 0; k0 < 1024; k0 += 32) {
        __syncthreads();
        glds16(ag0, lA0); glds16(ag1, lA1);
        glds16(bg, lB);
        ag0 += 32; ag1 += 32; bg += 32;
        __syncthreads();

        bf16x8 af[4], bfr[2];
        #pragma unroll
        for (int i = 0; i < 4; ++i)
            af[i] = *(const bf16x8*)&Ah[(wm + i * 16 + l15) * 32 + fpos];
        #pragma unroll
        for (int j = 0; j < 2; ++j)
            bfr[j] = *(const bf16x8*)&Bh[(wn + j * 16 + l15) * 32 + fpos];
        #pragma unroll
        for (int i = 0; i < 4; ++i)
            #pragma unroll
            for (int j = 0; j < 2; ++j)
                acc[i][j] = mfma16(af[i], bfr[j], acc[i][j]);
    }

    #pragma unroll
    for (int j = 0; j < 2; ++j) {
        const int n = n0 + wn + j * 16 + l15;
        const float bn = bias[n];
        #pragma unroll
        for (int i = 0; i < 4; ++i) {
            const int mbase = m0 + wm + i * 16 + (lq << 2);
            #pragma unroll
            for (int r = 0; r < 4; ++r)
                C[((size_t)(mbase + r) << 10) + n] = acc[i][j][r] + bn;
        }
    }
}

// ---------------------------------------------------------------------------
// attn4: transposed-S flash attention (reference K/V swap). S^T = V@Q^T via
// 16x16x32 (C-layout col=i=l15, row=j=lq*4+r) -> exp'd scores ARE the
// A-fragments of PV MFMAs (zero P LDS traffic). l via MFMA against all-ones B.
// V and kt staged in LDS with 16B XOR swizzle. j-split z=2; partials merged
// by `combine`. Block: 4 waves x 32 i-rows = 128 rows; grid (16, 32, 2).
// K32 PV/lsum (v6): paf pairs concat into 16x16x32 A-frags.
//
// v10 = v6 byte-identical (floor for this decomposition). Closed branches:
// pipelining (v2/v3 compiler drains, v7 scratch spill), occupancy (v4/v5
// traffic explosion), KVBLK=128 (v8 L2 thrash), XCD-cluster (v9: FETCH
// 72->18.5MB proved the kernel is NOT fetch-limited; dur +3us). Floor is
// the VALU/exp chain + per-jc sync at 4 blocks/CU.
// ---------------------------------------------------------------------------
__global__ __launch_bounds__(256, 4) void attn4(
    const short* __restrict__ Qh, const short* __restrict__ Vh,
    const short* __restrict__ Kt, const unsigned long long* __restrict__ MW,
    short* __restrict__ Opart, float* __restrict__ lpart)
{
    __shared__ short Vs[64 * 64];    // [j][d], 16B-chunk xor-swizzled
    __shared__ short Ks[64 * 64];    // [d][j], 16B-chunk xor-swizzled

    const int t = threadIdx.x, wid = t >> 6, lane = t & 63;
    const int l15 = lane & 15, lq = lane >> 4;
    const int bh = blockIdx.y, b = bh >> 4;
    const int z = blockIdx.z;
    const int ib = (blockIdx.x << 7) + (wid << 5);
    const int jbase = z << 10;

    // Q B-frags: B[n=i][k=d], rows ib + it*16 + l15
    bf16x8 qf[2][2];
    #pragma unroll
    for (int it = 0; it < 2; ++it) {
        const short* qp = Qh + ((size_t)bh * 2048 + ib + it * 16 + l15) * 64 + (lq << 3);
        qf[it][0] = *(const bf16x8*)qp;
        qf[it][1] = *(const bf16x8*)(qp + 32);
    }

    // staging: each wave stages 16 rows of V and 16 d-rows of Kt
    const int sr = lane >> 3, pc = lane & 7;
    const int lc = pc ^ sr;                      // logical 16B chunk
    const int wr = wid << 4;
    const short* vsrc = Vh + (size_t)bh * 131072 + (size_t)(jbase + wr + sr) * 64 + (lc << 3);
    const short* ksrc = Kt + (size_t)bh * 131072 + (size_t)(wr + sr) * 2048 + jbase + (lc << 3);
    short* vdst = Vs + (wr << 6);
    short* kdst = Ks + (wr << 6);

    const unsigned long long* mwp0 = MW + ((size_t)b * 2048 + ib + l15) * 32 + (z << 4);
    const unsigned long long* mwp1 = mwp0 + (size_t)16 * 32;

    const int x7 = l15 & 7;
    int voff[2], koff[4];
    #pragma unroll
    for (int p = 0; p < 2; ++p) voff[p] = (((p << 2) + lq) ^ x7) << 3;
    #pragma unroll
    for (int jt = 0; jt < 4; ++jt) {
        const int c8 = (jt << 2) + lq;           // logical 8B chunk
        koff[jt] = (((c8 >> 1) ^ x7) << 3) + ((c8 & 1) << 2);
    }

    f32x4 O[2][4] = {};
    f32x4 lsum[2] = {};
    bf16x8 ones8;
    #pragma unroll
    for (int e = 0; e < 8; ++e) ones8[e] = (short)0x3F80;

    for (int jc = 0; jc < 16; ++jc) {
        __syncthreads();
        glds16(vsrc, vdst);
        glds16(vsrc + 512, vdst + 512);
        glds16(ksrc, kdst);
        glds16(ksrc + 8 * 2048, kdst + 512);
        vsrc += 4096; ksrc += 64;

        uint2 mword[2];
        mword[0] = *(const uint2*)(mwp0 + jc);
        mword[1] = *(const uint2*)(mwp1 + jc);
        __syncthreads();

        // V A-frags: A[m=j][k=d]
        bf16x8 vf[4][2];
        #pragma unroll
        for (int jt = 0; jt < 4; ++jt) {
            const short* vp = &Vs[((jt << 4) + l15) << 6];
            vf[jt][0] = *(const bf16x8*)(vp + voff[0]);
            vf[jt][1] = *(const bf16x8*)(vp + voff[1]);
        }

        // S^T tiles -> exp -> packed K32 P A-frags (registers), l via ones-MFMA
        bf16x8 pa[2][2];                         // [it][b2]: concat of jt=2b2,2b2+1
        #pragma unroll
        for (int it = 0; it < 2; ++it) {
            const unsigned wx = mword[it].x, wy = mword[it].y;
            #pragma unroll
            for (int b2 = 0; b2 < 2; ++b2) {
                uint4 uu4;
                unsigned* uw = (unsigned*)&uu4;
                #pragma unroll
                for (int h = 0; h < 2; ++h) {
                    const int jt = (b2 << 1) + h;
                    f32x4 sc = {};
                    sc = mfma16(vf[jt][0], qf[it][0], sc);
                    sc = mfma16(vf[jt][1], qf[it][1], sc);
                    const unsigned w32 = (jt < 2) ? wx : wy;
                    float p[4];
                    #pragma unroll
                    for (int r = 0; r < 4; ++r) {
                        const unsigned bit = (w32 >> (((jt & 1) << 4) + (lq << 2) + r)) & 1u;
                        const float e = EXP2F(sc[r]);
                        p[r] = bit ? e : 0.f;
                    }
                    uw[(h << 1) + 0] = pktrunc(p[0], p[1]);
                    uw[(h << 1) + 1] = pktrunc(p[2], p[3]);
                }
                pa[it][b2] = __builtin_bit_cast(bf16x8, uu4);
                lsum[it] = mfma16(pa[it][b2], ones8, lsum[it]);
            }
        }

        // O += P @ K : B[n=d][k=j] = concat of the two b64 Ks reads per pair
        #pragma unroll
        for (int dt = 0; dt < 4; ++dt) {
            const short* kp = &Ks[((dt << 4) + l15) << 6];
            #pragma unroll
            for (int b2 = 0; b2 < 2; ++b2) {
                const bf16x4 k0 = *(const bf16x4*)(kp + koff[(b2 << 1) + 0]);
                const bf16x4 k1 = *(const bf16x4*)(kp + koff[(b2 << 1) + 1]);
                const bf16x8 kk = cat44(k0, k1);
                O[0][dt] = mfma16(pa[0][b2], kk, O[0][dt]);
                O[1][dt] = mfma16(pa[1][b2], kk, O[1][dt]);
            }
        }
    }

    // epilogue: rows i = lq*4+r; cols d = dt*16+l15; l duplicated across l15
    const size_t zb = (size_t)((z << 5) + bh) * 2048;
    #pragma unroll
    for (int it = 0; it < 2; ++it) {
        const int rb = ib + (it << 4) + (lq << 2);
        if (l15 == 0) {
            #pragma unroll
            for (int r = 0; r < 4; ++r)
                lpart[zb + rb + r] = lsum[it][r];
        }
        #pragma unroll
        for (int dt = 0; dt < 4; ++dt)
            #pragma unroll
            for (int r = 0; r < 4; ++r)
                Opart[(zb + rb + r) * 64 + (dt << 4) + l15] = f2bf(O[it][dt][r]);
    }
}

// ---------------------------------------------------------------------------
// combine: attr[b][s][h*64+d] = (O0+O1)/(l0+l1), bf16 out
// ---------------------------------------------------------------------------
__global__ __launch_bounds__(256) void combine(const short* __restrict__ Op,
                                               const float* __restrict__ lp,
                                               short* __restrict__ attr) {
    const int idx = blockIdx.x * 256 + threadIdx.x;      // 524288 total
    const int d8 = (idx & 7) << 3;
    const int srow = (idx >> 3) & 2047;
    const int bh = idx >> 14, b = bh >> 4, h = bh & 15;
    const size_t r0 = (size_t)bh * 2048 + srow;
    const size_t r1 = r0 + (size_t)32 * 2048;
    uint4 a = *(const uint4*)(Op + r0 * 64 + d8);
    uint4 c = *(const uint4*)(Op + r1 * 64 + d8);
    const float inv = 1.f / (lp[r0] + lp[r1]);
    const unsigned* au = (const unsigned*)&a;
    const unsigned* cu = (const unsigned*)&c;
    short o[8];
    #pragma unroll
    for (int i = 0; i < 4; ++i) {
        const float a0 = __uint_as_float(au[i] << 16);
        const float a1 = __uint_as_float(au[i] & 0xFFFF0000u);
        const float c0 = __uint_as_float(cu[i] << 16);
        const float c1 = __uint_as_float(cu[i] & 0xFFFF0000u);
        o[2 * i + 0] = f2bf((a0 + c0) * inv);
        o[2 * i + 1] = f2bf((a1 + c1) * inv);
    }
    *(uint4*)&attr[((size_t)b * 2048 + srow) * 1024 + (h << 6) + d8] = *(uint4*)o;
}

// ---------------------------------------------------------------------------
extern "C" void kernel_launch(void* const* d_in, const int* in_sizes, int n_in,
                              void* d_out, int out_size, void* d_ws, size_t ws_size,
                              hipStream_t stream) {
    const float* value = (const float*)d_in[0];
    const float* key   = (const float*)d_in[1];
    const float* query = (const float*)d_in[2];
    const int*   mask  = (const int*)d_in[3];
    const float* bv = (const float*)d_in[5];
    const float* bk = (const float*)d_in[7];
    const float* bq = (const float*)d_in[9];
    const float* bo = (const float*)d_in[11];
    float* out = (float*)d_out;

    const size_t M1 = (size_t)1 << 20, M4 = (size_t)1 << 22;
    short* ws = (short*)d_ws;
    short* Xq = ws;                       // reused as attr after proj
    short* Xk = ws + M4;                  // reused as Opart after proj (2*M4)
    short* Xv = ws + 2 * M4;
    short* Wc0 = ws + 3 * M4;             // reused as lpart after proj
    short* Wc1 = Wc0 + M1;
    short* Wc2 = Wc1 + M1;
    short* Wc3 = Wc2 + M1;
    short* qh = ws + 4 * M4;
    short* kt = ws + 5 * M4;
    short* vh = ws + 6 * M4;
    unsigned long long* maskw = (unsigned long long*)(ws + 7 * M4);
    short* attr = Xq;
    short* Opart = Xk;
    float* lpart = (float*)Wc0;

    CvtArgs cv;
    cv.src[0] = query; cv.dst[0] = Xq;
    cv.src[1] = key;   cv.dst[1] = Xk;
    cv.src[2] = value; cv.dst[2] = Xv;
    cv.src[3] = (const float*)d_in[8];  cv.dst[3] = Wc0;  // Wq
    cv.src[4] = (const float*)d_in[6];  cv.dst[4] = Wc1;  // Wk
    cv.src[5] = (const float*)d_in[4];  cv.dst[5] = Wc2;  // Wv
    cv.src[6] = (const float*)d_in[10]; cv.dst[6] = Wc3;  // Wo
    prep<<<10240, 256, 0, stream>>>(cv, mask, maskw);

    GemmArgs g1;
    g1.X[0] = Xq;  g1.W[0] = Wc0; g1.B[0] = bq; g1.C[0] = qh; g1.scale[0] = QSCALE;
    g1.X[1] = Xv;  g1.W[1] = Wc2; g1.B[1] = bv; g1.C[1] = vh; g1.scale[1] = 1.f;
    g1.X[2] = Wc1; g1.W[2] = Xk;  g1.B[2] = bk; g1.C[2] = kt; g1.scale[2] = 1.f;  // transposed K
    gemm_bt<0><<<dim3(32, 8, 3), 256, 0, stream>>>(g1);

    attn4<<<dim3(16, 32, 2), 256, 0, stream>>>(qh, vh, kt, maskw, Opart, lpart);

    combine<<<2048, 256, 0, stream>>>(Opart, lpart, attr);

    gemm1_64<<<dim3(32, 16), 256, 0, stream>>>(attr, Wc3, bo, out);
}

// Round 12
// 255.793 us; speedup vs baseline: 1.3322x; 1.0484x over previous
//
#include <hip/hip_runtime.h>

#define S_LEN 2048
#define DMODEL 1024
#define NHEADS 16
#define DKH 64

typedef __attribute__((ext_vector_type(8))) short bf16x8;
typedef __attribute__((ext_vector_type(4))) short bf16x4;
typedef __attribute__((ext_vector_type(4))) float f32x4;

#if __has_builtin(__builtin_amdgcn_exp2f)
#define EXP2F(x) __builtin_amdgcn_exp2f(x)
#define QSCALE (0.125f * 1.44269504f)
#else
#define EXP2F(x) __expf(x)
#define QSCALE 0.125f
#endif

static __device__ __forceinline__ short f2bf(float f) {
    unsigned b = __float_as_uint(f);
    b = (b + 0x7FFFu + ((b >> 16) & 1u)) >> 16;   // RNE
    return (short)b;
}

// pack truncated-bf16 of (lo,hi) into one u32
static __device__ __forceinline__ unsigned pktrunc(float lo, float hi) {
#if __has_builtin(__builtin_amdgcn_perm)
    return __builtin_amdgcn_perm(__float_as_uint(hi), __float_as_uint(lo), 0x07060302u);
#else
    return (__float_as_uint(lo) >> 16) | (__float_as_uint(hi) & 0xFFFF0000u);
#endif
}

static __device__ __forceinline__ f32x4 mfma16(bf16x8 a, bf16x8 b, f32x4 c) {
    return __builtin_amdgcn_mfma_f32_16x16x32_bf16(a, b, c, 0, 0, 0);
}

static __device__ __forceinline__ bf16x8 cat44(bf16x4 a, bf16x4 b) {
    bf16x8 r;
    r[0] = a[0]; r[1] = a[1]; r[2] = a[2]; r[3] = a[3];
    r[4] = b[0]; r[5] = b[1]; r[6] = b[2]; r[7] = b[3];
    return r;
}

static __device__ __forceinline__ void glds16(const short* g, short* l) {
    __builtin_amdgcn_global_load_lds(
        (const __attribute__((address_space(1))) void*)g,
        (__attribute__((address_space(3))) void*)l, 16, 0, 0);
}

// ---------------------------------------------------------------------------
// prep: fused fp32->bf16 convert (blocks 0..8191) + mask bit-pack (2048 blocks)
// ---------------------------------------------------------------------------
struct CvtArgs { const float* src[7]; short* dst[7]; };

__global__ __launch_bounds__(256) void prep(CvtArgs a, const int* __restrict__ mask,
                                            unsigned long long* __restrict__ mw) {
    if (blockIdx.x < 8192) {
        const size_t i8 = ((size_t)blockIdx.x * 256 + threadIdx.x) * 8;
        int seg; size_t off;
        if (i8 < ((size_t)12 << 20)) { seg = (int)(i8 >> 22); off = i8 & ((1u << 22) - 1); }
        else { size_t r = i8 - ((size_t)12 << 20); seg = 3 + (int)(r >> 20); off = r & ((1u << 20) - 1); }
        const float* s = a.src[seg] + off;
        float4 x0 = *(const float4*)s, x1 = *(const float4*)(s + 4);
        short o[8];
        o[0] = f2bf(x0.x); o[1] = f2bf(x0.y); o[2] = f2bf(x0.z); o[3] = f2bf(x0.w);
        o[4] = f2bf(x1.x); o[5] = f2bf(x1.y); o[6] = f2bf(x1.z); o[7] = f2bf(x1.w);
        *(uint4*)(a.dst[seg] + off) = *(uint4*)o;
    } else {
        const int wv = ((blockIdx.x - 8192) << 2) + (threadIdx.x >> 6);
        const int lane = threadIdx.x & 63;
        const size_t base = (size_t)wv << 4;
        #pragma unroll 4
        for (int it = 0; it < 16; ++it) {
            const size_t w = base + it;
            const int m = mask[(w << 6) + lane];
            unsigned long long bal = __ballot(m != 0);
            if (lane == 0) mw[w] = bal;
        }
    }
}

// ---------------------------------------------------------------------------
// gemm_bt: C = X @ W^T + bias (bf16), 128x128 tile, BK=64 (v11), glds16
// staging with 8-chunk XOR swizzle (stored chunk = pc^sr via pre-swizzled
// global src; read key = l15&7; 2-way bank aliasing = free, measured 0
// conflicts on the 4-chunk version). 16 K-steps instead of 32: per barrier
// drain, 32 MFMA instead of 16 (v10 PMC: MfmaUtil 16%, VALU 9% -> pure
// exposed drain latency; BK=64 halves drain events at same total bytes).
// LDS 32KB -> still 5 blocks/CU >= grid's 3. XCD-cluster tile swizzle.
// MODE 0: z<2 -> bf16 headed [BH][S][DKH] (scaled); z==2 -> TRANSPOSED headed
// kt[bh][d][s].
// ---------------------------------------------------------------------------
struct GemmArgs { const short* X[3]; const short* W[3]; const float* B[3];
                  void* C[3]; float scale[3]; };

template <int MODE>
__global__ __launch_bounds__(256) void gemm_bt(GemmArgs a) {
    __shared__ short Ah[128 * 64];
    __shared__ short Bh[128 * 64];
    const int z = blockIdx.z;
    const short* X = a.X[z];
    const short* W = a.W[z];
    const float* bias = a.B[z];
    const float scl = a.scale[z];

    const int t = threadIdx.x, wid = t >> 6, lane = t & 63;
    const int l15 = lane & 15, lq = lane >> 4;

    // XCD-cluster: lid in [0,256) per z; xcd = lid&7 (256%8==0 so z-invariant)
    const int lid = blockIdx.x + (blockIdx.y << 5);
    const int vm = ((lid & 7) << 2) + ((lid >> 3) & 3);   // [0,32)
    const int vn = lid >> 5;                              // [0,8)

    int m0, n0;
    if (MODE == 0 && z == 2) { m0 = vn << 7; n0 = vm << 7; }
    else                     { m0 = vm << 7; n0 = vn << 7; }
    const int wm = (wid >> 1) << 6, wn = (wid & 1) << 6;

    // staging: sr = row in 8-group, pc = chunk; global chunk pre-swizzled pc^sr
    const int sr = lane >> 3, pc = lane & 7;
    const int scol = (pc ^ sr) << 3;
    const int arow = (wid << 5) + sr;                     // wave's 32-row base
    const short* ag = X + (size_t)(m0 + arow) * 1024 + scol;
    const short* bg = W + (size_t)(n0 + arow) * 1024 + scol;
    short* lA = Ah + (wid << 5) * 64;
    short* lB = Bh + (wid << 5) * 64;

    // read: chunk (kk*4+lq) ^ (row&7); row&7 == l15&7 for all frag rows
    const int key = l15 & 7;
    const int fpk0 = ((lq)     ^ key) << 3;
    const int fpk1 = ((lq + 4) ^ key) << 3;

    f32x4 acc[4][4] = {};

    for (int k0 = 0; k0 < 1024; k0 += 64) {
        __syncthreads();
        glds16(ag,             lA);
        glds16(ag +  8 * 1024, lA +  8 * 64);
        glds16(ag + 16 * 1024, lA + 16 * 64);
        glds16(ag + 24 * 1024, lA + 24 * 64);
        glds16(bg,             lB);
        glds16(bg +  8 * 1024, lB +  8 * 64);
        glds16(bg + 16 * 1024, lB + 16 * 64);
        glds16(bg + 24 * 1024, lB + 24 * 64);
        ag += 64; bg += 64;
        __syncthreads();

        #pragma unroll
        for (int kk = 0; kk < 2; ++kk) {
            const int fp = kk ? fpk1 : fpk0;
            bf16x8 af[4], bfr[4];
            #pragma unroll
            for (int i = 0; i < 4; ++i)
                af[i] = *(const bf16x8*)&Ah[(wm + i * 16 + l15) * 64 + fp];
            #pragma unroll
            for (int j = 0; j < 4; ++j)
                bfr[j] = *(const bf16x8*)&Bh[(wn + j * 16 + l15) * 64 + fp];
            #pragma unroll
            for (int i = 0; i < 4; ++i)
                #pragma unroll
                for (int j = 0; j < 4; ++j)
                    acc[i][j] = mfma16(af[i], bfr[j], acc[i][j]);
        }
    }

    if (MODE == 0 && z == 2) {
        // transposed headed write: kt[(b*16+h)*64+d][s], o = m-row feature
        #pragma unroll
        for (int i = 0; i < 4; ++i) {
            #pragma unroll
            for (int r = 0; r < 4; ++r) {
                const int o = m0 + wm + i * 16 + (lq << 2) + r;
                const float bo_ = bias[o];
                const int h = o >> 6, d = o & 63;
                #pragma unroll
                for (int j = 0; j < 4; ++j) {
                    const int n = n0 + wn + j * 16 + l15;
                    const int bb = n >> 11, s = n & 2047;
                    ((short*)a.C[2])[(((size_t)((bb * 16 + h) << 6) + d) << 11) + s] =
                        f2bf(acc[i][j][r] + bo_);
                }
            }
        }
        return;
    }

    #pragma unroll
    for (int j = 0; j < 4; ++j) {
        const int n = n0 + wn + j * 16 + l15;
        const float bn = bias[n];
        #pragma unroll
        for (int i = 0; i < 4; ++i) {
            const int mbase = m0 + wm + i * 16 + (lq << 2);
            #pragma unroll
            for (int r = 0; r < 4; ++r) {
                const float val = (acc[i][j][r] + bn) * scl;
                const int m = mbase + r;
                if (MODE == 0) {
                    const int b = m >> 11, s = m & 2047, h = n >> 6, d = n & 63;
                    ((short*)a.C[z])[((((size_t)(b * 16 + h)) << 11) + s) * 64 + d] = f2bf(val);
                } else {
                    ((float*)a.C[z])[((size_t)m << 10) + n] = val;
                }
            }
        }
    }
}

// ---------------------------------------------------------------------------
// gemm1_64: out = attr @ Wo^T + bo, fp32 out. 128x64 tiles, grid (32,16) =
// 512 blocks = 2 blocks/CU. v11: BK=64 (same transformation as gemm_bt):
// 16 K-steps, per step 6 glds16 + 2x(6 ds_read + 8 MFMA). LDS 24KB.
// ---------------------------------------------------------------------------
__global__ __launch_bounds__(256) void gemm1_64(const short* __restrict__ X,
                                                const short* __restrict__ W,
                                                const float* __restrict__ bias,
                                                float* __restrict__ C) {
    __shared__ short Ah[128 * 64];
    __shared__ short Bh[64 * 64];

    const int t = threadIdx.x, wid = t >> 6, lane = t & 63;
    const int l15 = lane & 15, lq = lane >> 4;

    const int lid = blockIdx.x + (blockIdx.y << 5);       // [0,512)
    const int vm = ((lid & 7) << 2) + ((lid >> 3) & 3);   // [0,32)
    const int vn = lid >> 5;                              // [0,16)
    const int m0 = vm << 7, n0 = vn << 6;
    const int wm = (wid >> 1) << 6, wn = (wid & 1) << 5;

    const int sr = lane >> 3, pc = lane & 7;
    const int scol = (pc ^ sr) << 3;
    const short* ag = X + (size_t)(m0 + (wid << 5) + sr) * 1024 + scol;
    const short* bg = W + (size_t)(n0 + (wid << 4) + sr) * 1024 + scol;
    short* lA = Ah + (wid << 5) * 64;
    short* lB = Bh + (wid << 4) * 64;

    const int key = l15 & 7;
    const int fpk0 = ((lq)     ^ key) << 3;
    const int fpk1 = ((lq + 4) ^ key) << 3;

    f32x4 acc[4][2] = {};

    for (int k0 = 0; k0 < 1024; k0 += 64) {
        __syncthreads();
        glds16(ag,             lA);
        glds16(ag +  8 * 1024, lA +  8 * 64);
        glds16(ag + 16 * 1024, lA + 16 * 64);
        glds16(ag + 24 * 1024, lA + 24 * 64);
        glds16(bg,             lB);
        glds16(bg +  8 * 1024, lB +  8 * 64);
        ag += 64; bg += 64;
        __syncthreads();

        #pragma unroll
        for (int kk = 0; kk < 2; ++kk) {
            const int fp = kk ? fpk1 : fpk0;
            bf16x8 af[4], bfr[2];
            #pragma unroll
            for (int i = 0; i < 4; ++i)
                af[i] = *(const bf16x8*)&Ah[(wm + i * 16 + l15) * 64 + fp];
            #pragma unroll
            for (int j = 0; j < 2; ++j)
                bfr[j] = *(const bf16x8*)&Bh[(wn + j * 16 + l15) * 64 + fp];
            #pragma unroll
            for (int i = 0; i < 4; ++i)
                #pragma unroll
                for (int j = 0; j < 2; ++j)
                    acc[i][j] = mfma16(af[i], bfr[j], acc[i][j]);
        }
    }

    #pragma unroll
    for (int j = 0; j < 2; ++j) {
        const int n = n0 + wn + j * 16 + l15;
        const float bn = bias[n];
        #pragma unroll
        for (int i = 0; i < 4; ++i) {
            const int mbase = m0 + wm + i * 16 + (lq << 2);
            #pragma unroll
            for (int r = 0; r < 4; ++r)
                C[((size_t)(mbase + r) << 10) + n] = acc[i][j][r] + bn;
        }
    }
}

// ---------------------------------------------------------------------------
// attn4: transposed-S flash attention (reference K/V swap). S^T = V@Q^T via
// 16x16x32 (C-layout col=i=l15, row=j=lq*4+r) -> exp'd scores ARE the
// A-fragments of PV MFMAs (zero P LDS traffic). l via MFMA against all-ones B.
// V and kt staged in LDS with 16B XOR swizzle. j-split z=2; partials merged
// by `combine`. Block: 4 waves x 32 i-rows = 128 rows; grid (16, 32, 2).
// K32 PV/lsum (v6). At its structural floor (~56.5us): pipelining, occupancy,
// KVBLK=128, XCD-cluster all closed (v2-v9).
// ---------------------------------------------------------------------------
__global__ __launch_bounds__(256, 4) void attn4(
    const short* __restrict__ Qh, const short* __restrict__ Vh,
    const short* __restrict__ Kt, const unsigned long long* __restrict__ MW,
    short* __restrict__ Opart, float* __restrict__ lpart)
{
    __shared__ short Vs[64 * 64];    // [j][d], 16B-chunk xor-swizzled
    __shared__ short Ks[64 * 64];    // [d][j], 16B-chunk xor-swizzled

    const int t = threadIdx.x, wid = t >> 6, lane = t & 63;
    const int l15 = lane & 15, lq = lane >> 4;
    const int bh = blockIdx.y, b = bh >> 4;
    const int z = blockIdx.z;
    const int ib = (blockIdx.x << 7) + (wid << 5);
    const int jbase = z << 10;

    // Q B-frags: B[n=i][k=d], rows ib + it*16 + l15
    bf16x8 qf[2][2];
    #pragma unroll
    for (int it = 0; it < 2; ++it) {
        const short* qp = Qh + ((size_t)bh * 2048 + ib + it * 16 + l15) * 64 + (lq << 3);
        qf[it][0] = *(const bf16x8*)qp;
        qf[it][1] = *(const bf16x8*)(qp + 32);
    }

    // staging: each wave stages 16 rows of V and 16 d-rows of Kt
    const int sr = lane >> 3, pc = lane & 7;
    const int lc = pc ^ sr;                      // logical 16B chunk
    const int wr = wid << 4;
    const short* vsrc = Vh + (size_t)bh * 131072 + (size_t)(jbase + wr + sr) * 64 + (lc << 3);
    const short* ksrc = Kt + (size_t)bh * 131072 + (size_t)(wr + sr) * 2048 + jbase + (lc << 3);
    short* vdst = Vs + (wr << 6);
    short* kdst = Ks + (wr << 6);

    const unsigned long long* mwp0 = MW + ((size_t)b * 2048 + ib + l15) * 32 + (z << 4);
    const unsigned long long* mwp1 = mwp0 + (size_t)16 * 32;

    const int x7 = l15 & 7;
    int voff[2], koff[4];
    #pragma unroll
    for (int p = 0; p < 2; ++p) voff[p] = (((p << 2) + lq) ^ x7) << 3;
    #pragma unroll
    for (int jt = 0; jt < 4; ++jt) {
        const int c8 = (jt << 2) + lq;           // logical 8B chunk
        koff[jt] = (((c8 >> 1) ^ x7) << 3) + ((c8 & 1) << 2);
    }

    f32x4 O[2][4] = {};
    f32x4 lsum[2] = {};
    bf16x8 ones8;
    #pragma unroll
    for (int e = 0; e < 8; ++e) ones8[e] = (short)0x3F80;

    for (int jc = 0; jc < 16; ++jc) {
        __syncthreads();
        glds16(vsrc, vdst);
        glds16(vsrc + 512, vdst + 512);
        glds16(ksrc, kdst);
        glds16(ksrc + 8 * 2048, kdst + 512);
        vsrc += 4096; ksrc += 64;

        uint2 mword[2];
        mword[0] = *(const uint2*)(mwp0 + jc);
        mword[1] = *(const uint2*)(mwp1 + jc);
        __syncthreads();

        // V A-frags: A[m=j][k=d]
        bf16x8 vf[4][2];
        #pragma unroll
        for (int jt = 0; jt < 4; ++jt) {
            const short* vp = &Vs[((jt << 4) + l15) << 6];
            vf[jt][0] = *(const bf16x8*)(vp + voff[0]);
            vf[jt][1] = *(const bf16x8*)(vp + voff[1]);
        }

        // S^T tiles -> exp -> packed K32 P A-frags (registers), l via ones-MFMA
        bf16x8 pa[2][2];                         // [it][b2]: concat of jt=2b2,2b2+1
        #pragma unroll
        for (int it = 0; it < 2; ++it) {
            const unsigned wx = mword[it].x, wy = mword[it].y;
            #pragma unroll
            for (int b2 = 0; b2 < 2; ++b2) {
                uint4 uu4;
                unsigned* uw = (unsigned*)&uu4;
                #pragma unroll
                for (int h = 0; h < 2; ++h) {
                    const int jt = (b2 << 1) + h;
                    f32x4 sc = {};
                    sc = mfma16(vf[jt][0], qf[it][0], sc);
                    sc = mfma16(vf[jt][1], qf[it][1], sc);
                    const unsigned w32 = (jt < 2) ? wx : wy;
                    float p[4];
                    #pragma unroll
                    for (int r = 0; r < 4; ++r) {
                        const unsigned bit = (w32 >> (((jt & 1) << 4) + (lq << 2) + r)) & 1u;
                        const float e = EXP2F(sc[r]);
                        p[r] = bit ? e : 0.f;
                    }
                    uw[(h << 1) + 0] = pktrunc(p[0], p[1]);
                    uw[(h << 1) + 1] = pktrunc(p[2], p[3]);
                }
                pa[it][b2] = __builtin_bit_cast(bf16x8, uu4);
                lsum[it] = mfma16(pa[it][b2], ones8, lsum[it]);
            }
        }

        // O += P @ K : B[n=d][k=j] = concat of the two b64 Ks reads per pair
        #pragma unroll
        for (int dt = 0; dt < 4; ++dt) {
            const short* kp = &Ks[((dt << 4) + l15) << 6];
            #pragma unroll
            for (int b2 = 0; b2 < 2; ++b2) {
                const bf16x4 k0 = *(const bf16x4*)(kp + koff[(b2 << 1) + 0]);
                const bf16x4 k1 = *(const bf16x4*)(kp + koff[(b2 << 1) + 1]);
                const bf16x8 kk = cat44(k0, k1);
                O[0][dt] = mfma16(pa[0][b2], kk, O[0][dt]);
                O[1][dt] = mfma16(pa[1][b2], kk, O[1][dt]);
            }
        }
    }

    // epilogue: rows i = lq*4+r; cols d = dt*16+l15; l duplicated across l15
    const size_t zb = (size_t)((z << 5) + bh) * 2048;
    #pragma unroll
    for (int it = 0; it < 2; ++it) {
        const int rb = ib + (it << 4) + (lq << 2);
        if (l15 == 0) {
            #pragma unroll
            for (int r = 0; r < 4; ++r)
                lpart[zb + rb + r] = lsum[it][r];
        }
        #pragma unroll
        for (int dt = 0; dt < 4; ++dt)
            #pragma unroll
            for (int r = 0; r < 4; ++r)
                Opart[(zb + rb + r) * 64 + (dt << 4) + l15] = f2bf(O[it][dt][r]);
    }
}

// ---------------------------------------------------------------------------
// combine: attr[b][s][h*64+d] = (O0+O1)/(l0+l1), bf16 out
// ---------------------------------------------------------------------------
__global__ __launch_bounds__(256) void combine(const short* __restrict__ Op,
                                               const float* __restrict__ lp,
                                               short* __restrict__ attr) {
    const int idx = blockIdx.x * 256 + threadIdx.x;      // 524288 total
    const int d8 = (idx & 7) << 3;
    const int srow = (idx >> 3) & 2047;
    const int bh = idx >> 14, b = bh >> 4, h = bh & 15;
    const size_t r0 = (size_t)bh * 2048 + srow;
    const size_t r1 = r0 + (size_t)32 * 2048;
    uint4 a = *(const uint4*)(Op + r0 * 64 + d8);
    uint4 c = *(const uint4*)(Op + r1 * 64 + d8);
    const float inv = 1.f / (lp[r0] + lp[r1]);
    const unsigned* au = (const unsigned*)&a;
    const unsigned* cu = (const unsigned*)&c;
    short o[8];
    #pragma unroll
    for (int i = 0; i < 4; ++i) {
        const float a0 = __uint_as_float(au[i] << 16);
        const float a1 = __uint_as_float(au[i] & 0xFFFF0000u);
        const float c0 = __uint_as_float(cu[i] << 16);
        const float c1 = __uint_as_float(cu[i] & 0xFFFF0000u);
        o[2 * i + 0] = f2bf((a0 + c0) * inv);
        o[2 * i + 1] = f2bf((a1 + c1) * inv);
    }
    *(uint4*)&attr[((size_t)b * 2048 + srow) * 1024 + (h << 6) + d8] = *(uint4*)o;
}

// ---------------------------------------------------------------------------
extern "C" void kernel_launch(void* const* d_in, const int* in_sizes, int n_in,
                              void* d_out, int out_size, void* d_ws, size_t ws_size,
                              hipStream_t stream) {
    const float* value = (const float*)d_in[0];
    const float* key   = (const float*)d_in[1];
    const float* query = (const float*)d_in[2];
    const int*   mask  = (const int*)d_in[3];
    const float* bv = (const float*)d_in[5];
    const float* bk = (const float*)d_in[7];
    const float* bq = (const float*)d_in[9];
    const float* bo = (const float*)d_in[11];
    float* out = (float*)d_out;

    const size_t M1 = (size_t)1 << 20, M4 = (size_t)1 << 22;
    short* ws = (short*)d_ws;
    short* Xq = ws;                       // reused as attr after proj
    short* Xk = ws + M4;                  // reused as Opart after proj (2*M4)
    short* Xv = ws + 2 * M4;
    short* Wc0 = ws + 3 * M4;             // reused as lpart after proj
    short* Wc1 = Wc0 + M1;
    short* Wc2 = Wc1 + M1;
    short* Wc3 = Wc2 + M1;
    short* qh = ws + 4 * M4;
    short* kt = ws + 5 * M4;
    short* vh = ws + 6 * M4;
    unsigned long long* maskw = (unsigned long long*)(ws + 7 * M4);
    short* attr = Xq;
    short* Opart = Xk;
    float* lpart = (float*)Wc0;

    CvtArgs cv;
    cv.src[0] = query; cv.dst[0] = Xq;
    cv.src[1] = key;   cv.dst[1] = Xk;
    cv.src[2] = value; cv.dst[2] = Xv;
    cv.src[3] = (const float*)d_in[8];  cv.dst[3] = Wc0;  // Wq
    cv.src[4] = (const float*)d_in[6];  cv.dst[4] = Wc1;  // Wk
    cv.src[5] = (const float*)d_in[4];  cv.dst[5] = Wc2;  // Wv
    cv.src[6] = (const float*)d_in[10]; cv.dst[6] = Wc3;  // Wo
    prep<<<10240, 256, 0, stream>>>(cv, mask, maskw);

    GemmArgs g1;
    g1.X[0] = Xq;  g1.W[0] = Wc0; g1.B[0] = bq; g1.C[0] = qh; g1.scale[0] = QSCALE;
    g1.X[1] = Xv;  g1.W[1] = Wc2; g1.B[1] = bv; g1.C[1] = vh; g1.scale[1] = 1.f;
    g1.X[2] = Wc1; g1.W[2] = Xk;  g1.B[2] = bk; g1.C[2] = kt; g1.scale[2] = 1.f;  // transposed K
    gemm_bt<0><<<dim3(32, 8, 3), 256, 0, stream>>>(g1);

    attn4<<<dim3(16, 32, 2), 256, 0, stream>>>(qh, vh, kt, maskw, Opart, lpart);

    combine<<<2048, 256, 0, stream>>>(Opart, lpart, attr);

    gemm1_64<<<dim3(32, 16), 256, 0, stream>>>(attr, Wc3, bo, out);
}